// Round 3
// baseline (753.646 us; speedup 1.0000x reference)
//
#include <hip/hip_runtime.h>
#include <hip/hip_bf16.h>
#include <cstddef>

// Problem constants (match reference).
#define NQ 8192
#define DD 1024

typedef __attribute__((ext_vector_type(8))) short s8v;     // 8 bf16 (4 VGPR)
typedef __attribute__((ext_vector_type(8))) int i8v;       // 32 fp8 bytes (8 VGPR)
typedef __attribute__((ext_vector_type(4))) float f32x4;   // 16x16 C/D frag
typedef __attribute__((ext_vector_type(16))) float f32x16; // 32x32 C/D frag

typedef const __attribute__((address_space(1))) unsigned int* gptr_t;
typedef __attribute__((address_space(3))) unsigned int* lptr_t;

#define SCALE_1_16 0x7B7B7B7Bu   // E8M0 123 = 2^-4 (qk: undo 16x pre-scale twice)
#define SCALE_1_128 0x78787878u  // E8M0 120 = 2^-7 (pv A: undo 128x d-scale)
#define SCALE_1    0x7F7F7F7Fu   // E8M0 127 = 2^0  (pv B)

__device__ inline unsigned short f2bf(float f) {
  union { float f; unsigned u; } v; v.f = f;
  unsigned r = (v.u + 0x7FFFu + ((v.u >> 16) & 1u)) >> 16;  // RNE
  return (unsigned short)r;
}
__device__ inline float bits2f(unsigned u) {
  union { unsigned u; float f; } v; v.u = u;
  return v.f;
}

// f32 -> OCP e4m3 bits, RNE, clamp to +-448.
__device__ inline unsigned char f2e4m3(float x) {
  union { float f; unsigned u; } v; v.f = x;
  const unsigned s = (v.u >> 31) << 7;
  unsigned au = v.u & 0x7FFFFFFFu;
  if (au > 0x43E00000u) au = 0x43E00000u;  // clamp |x| to 448.0
  if (au >= 0x3C800000u) {                 // |x| >= 2^-6: e4m3 normal
    const unsigned rounded = au + 0x7FFFFu + ((au >> 20) & 1u);  // RNE @ 3 mant
    const unsigned e8 = ((rounded >> 23) & 0xFF) - 120u;         // -127+7
    const unsigned m8 = (rounded >> 20) & 7u;
    return (unsigned char)(s | (e8 << 3) | m8);
  } else {                                 // subnormal
    union { unsigned u; float f; } a; a.u = au;
    const unsigned q = (unsigned)rintf(a.f * 512.0f);  // 0..8
    return (unsigned char)(s | q);
  }
}

// Register-only combine of two 16-B LDS loads into one fp8 MFMA operand.
__device__ inline i8v make_i8v(int4 a, int4 b) {
  i8v v;
  v[0] = a.x; v[1] = a.y; v[2] = a.z; v[3] = a.w;
  v[4] = b.x; v[5] = b.y; v[6] = b.z; v[7] = b.w;
  return v;
}

// ---------------------------------------------------------------------------
// m97-style bf16 MFMA main loop: C(128x128) += A(128xK) @ B(128xK)^T.
// Used by proj_gemm only now.  XOR-swizzled 16-B chunks, 0 bank conflicts
// (verified round-0).
// ---------------------------------------------------------------------------
template <int KDIM, int ASTR, int BSTR>
__device__ inline void mfma_core(const unsigned short* __restrict__ A,
                                 const unsigned short* __restrict__ B,
                                 int i0, int j0, int tid,
                                 unsigned short* AsU, unsigned short* BsU,
                                 f32x4 (&acc)[4][4]) {
  const int lane = tid & 63;
  const int w = tid >> 6;
  const int wr = (w >> 1) * 64;
  const int wc = (w & 1) * 64;
  const int l16 = lane & 15;
  const int lq = lane >> 4;
  const int srow = lane >> 3;                          // 0..7
  const int scol = (((lane & 7) ^ (srow & 7)) * 8);    // swizzled 16-B chunk

  for (int kk = 0; kk < KDIM; kk += 64) {
    __syncthreads();
#pragma unroll
    for (int t = 0; t < 4; t++) {
      const int r0 = w * 32 + t * 8;
      const unsigned short* g = &A[(size_t)(i0 + r0 + srow) * ASTR + kk + scol];
      __builtin_amdgcn_global_load_lds((gptr_t)(const void*)g,
                                       (lptr_t)(void*)&AsU[r0 * 64], 16, 0, 0);
    }
#pragma unroll
    for (int t = 0; t < 4; t++) {
      const int r0 = w * 32 + t * 8;
      const unsigned short* g = &B[(size_t)(j0 + r0 + srow) * BSTR + kk + scol];
      __builtin_amdgcn_global_load_lds((gptr_t)(const void*)g,
                                       (lptr_t)(void*)&BsU[r0 * 64], 16, 0, 0);
    }
    __syncthreads();

    const int h = l16 & 7;
    s8v af[4][2], bf[4][2];
#pragma unroll
    for (int t = 0; t < 4; t++)
#pragma unroll
      for (int s = 0; s < 2; s++) {
        const int ch = ((s * 4 + lq) ^ h) * 8;  // swizzled chunk offset
        af[t][s] = *(const s8v*)&AsU[(wr + 16 * t + l16) * 64 + ch];
        bf[t][s] = *(const s8v*)&BsU[(wc + 16 * t + l16) * 64 + ch];
      }
#pragma unroll
    for (int s = 0; s < 2; s++)
#pragma unroll
      for (int a = 0; a < 4; a++)
#pragma unroll
        for (int b = 0; b < 4; b++)
          acc[a][b] = __builtin_amdgcn_mfma_f32_16x16x32_bf16(
              af[a][s], bf[b][s], acc[a][b], 0, 0, 0);
  }
}

// ---------------------------------------------------------------------------
// fp32 -> bf16 elementwise.
// ---------------------------------------------------------------------------
__global__ void f32_to_bf16(const float* __restrict__ in,
                            unsigned short* __restrict__ out, int n4) {
  int i = (blockIdx.x * blockDim.x + threadIdx.x);
  if (i < n4) {
    const float4 v = *(const float4*)&in[i * 4];
    ushort4 o;
    o.x = f2bf(v.x); o.y = f2bf(v.y); o.z = f2bf(v.z); o.w = f2bf(v.w);
    *(ushort4*)&out[i * 4] = o;
  }
}

__global__ void zero_f32(float* __restrict__ p, int n) {
  const int i = blockIdx.x * blockDim.x + threadIdx.x;
  if (i < n) p[i] = 0.f;
}

// ---------------------------------------------------------------------------
// fp32 [R][C] -> bf16 [C][R] transpose+convert (32x32 LDS tiles).
// ---------------------------------------------------------------------------
__global__ void transpose_cvt(const float* __restrict__ in,
                              unsigned short* __restrict__ out, int R, int C) {
  __shared__ float t[32][33];
  const int bx = blockIdx.x;
  const int by = blockIdx.y;
  const int x = threadIdx.x & 31;
  const int y = threadIdx.x >> 5;
#pragma unroll
  for (int i = 0; i < 32; i += 8)
    t[y + i][x] = in[(size_t)(by * 32 + y + i) * C + bx * 32 + x];
  __syncthreads();
#pragma unroll
  for (int i = 0; i < 32; i += 8)
    out[(size_t)(bx * 32 + y + i) * R + by * 32 + x] = f2bf(t[x][y + i]);
}

// ---------------------------------------------------------------------------
// Projection GEMM: C[m][n] = sum_k A[m][k] * BT[n][k], bf16 in, K=1024.
// OUTMODE 1: e4m3(16*v) only (xif).   OUTMODE 2: bf16 AND e4m3(v) (supT+supT8).
// ---------------------------------------------------------------------------
template <int NST, int OUTMODE>
__global__ __launch_bounds__(256, 2)
void proj_gemm(const unsigned short* __restrict__ A,
               const unsigned short* __restrict__ BT,
               void* __restrict__ C1, void* __restrict__ C2) {
  __shared__ __align__(16) unsigned short As[128 * 64];
  __shared__ __align__(16) unsigned short Bs[128 * 64];
  const int tid = threadIdx.x;
  const int m0 = blockIdx.y * 128;
  const int n0 = blockIdx.x * 128;

  f32x4 acc[4][4];
#pragma unroll
  for (int a = 0; a < 4; a++)
#pragma unroll
    for (int b = 0; b < 4; b++) acc[a][b] = (f32x4){0.f, 0.f, 0.f, 0.f};

  mfma_core<DD, DD, DD>(A, BT, m0, n0, tid, As, Bs, acc);

  const int lane = tid & 63;
  const int w = tid >> 6;
  const int wr = (w >> 1) * 64, wc = (w & 1) * 64;
  const int l16 = lane & 15, lq = lane >> 4;
#pragma unroll
  for (int ti = 0; ti < 4; ti++)
#pragma unroll
    for (int r = 0; r < 4; r++) {
      const int row = m0 + wr + 16 * ti + lq * 4 + r;
#pragma unroll
      for (int tj = 0; tj < 4; tj++) {
        const int col = n0 + wc + 16 * tj + l16;
        const size_t idx = (size_t)row * NST + col;
        const float v = acc[ti][tj][r];
        if (OUTMODE == 1) {
          ((unsigned char*)C1)[idx] = f2e4m3(v * 16.f);
        } else {
          ((unsigned short*)C1)[idx] = f2bf(v);
          if (OUTMODE == 2) ((unsigned char*)C2)[idx] = f2e4m3(v);
        }
      }
    }
}

// ---------------------------------------------------------------------------
// colV[n] = sum_j supT[n][j]  (bf16 input, exact fp32 accumulate).
// One block per n-row; the old row_sum body.
// ---------------------------------------------------------------------------
__global__ __launch_bounds__(256, 4)
void colsum_bf16(const unsigned short* __restrict__ supT,
                 float* __restrict__ colV) {
  const int row = blockIdx.x;
  const int tid = threadIdx.x;
  const unsigned short* pr = &supT[(size_t)row * NQ];
  float s = 0.f;
#pragma unroll
  for (int i = 0; i < 4; i++) {
    const int4 q = *(const int4*)&pr[(size_t)(tid + i * 256) * 8];
    s += bits2f((unsigned)q.x << 16) + bits2f((unsigned)q.x & 0xFFFF0000u);
    s += bits2f((unsigned)q.y << 16) + bits2f((unsigned)q.y & 0xFFFF0000u);
    s += bits2f((unsigned)q.z << 16) + bits2f((unsigned)q.z & 0xFFFF0000u);
    s += bits2f((unsigned)q.w << 16) + bits2f((unsigned)q.w & 0xFFFF0000u);
  }
#pragma unroll
  for (int m = 32; m >= 1; m >>= 1) s += __shfl_xor(s, m);
  __shared__ float red[4];
  if ((tid & 63) == 0) red[tid >> 6] = s;
  __syncthreads();
  if (tid == 0) colV[row] = red[0] + red[1] + red[2] + red[3];
}

// ---------------------------------------------------------------------------
// Pass 1: Pd = e4m3(128*(exp(s)-1)) where s = xi @ xi^T, via MX fp8 MFMA.
// P = 1 + d decomposition: |s| <~ 0.2 off-diag (diag ~1.05), so d*128 fits
// e4m3 (<=238).  Halves P traffic: 64 MB write here, 64 MB read in pv.
// lsum accumulates sum_j (p-1) via padded-LDS partials + 1 atomicAdd/row.
// ---------------------------------------------------------------------------
__global__ __launch_bounds__(256, 3)
void qk_fp8(const unsigned char* __restrict__ xif,  // [8192][1024] e4m3(16*xi)
            unsigned char* __restrict__ Pd,         // [8192][8192] e4m3(128*d)
            float* __restrict__ lsum) {             // [8192] fp32 (pre-zeroed)
  __shared__ __align__(16) unsigned char AsF[128 * 64];
  __shared__ __align__(16) unsigned char BsF[128 * 64];
  __shared__ float lsums[128][65];                  // padded, conflict-free
  const int tid = threadIdx.x;
  const int lane = tid & 63;
  const int w = tid >> 6;
  const int i0 = blockIdx.y * 128;
  const int j0 = blockIdx.x * 128;

  f32x16 acc[2][2];
#pragma unroll
  for (int a = 0; a < 2; a++)
#pragma unroll
    for (int b = 0; b < 2; b++)
#pragma unroll
      for (int r = 0; r < 16; r++) acc[a][b][r] = 0.f;

  const int srow = lane >> 2;  // 0..15: row within 16-row staging group
  const int slot = lane & 3;   // 16-B chunk slot within the row
  const int kb = lane >> 5;    // frag k-block (0/1)
  const int l31 = lane & 31;

  for (int kk = 0; kk < DD; kk += 64) {
    __syncthreads();
#pragma unroll
    for (int t = 0; t < 2; t++) {
      const int r = w * 32 + t * 16 + srow;
      const int c = slot ^ ((r >> 1) & 3);  // logical chunk for this slot
      const unsigned char* ga = &xif[(size_t)(i0 + r) * DD + kk + c * 16];
      const unsigned char* gb = &xif[(size_t)(j0 + r) * DD + kk + c * 16];
      __builtin_amdgcn_global_load_lds((gptr_t)(const void*)ga,
                                       (lptr_t)(void*)&AsF[(w * 32 + t * 16) * 64],
                                       16, 0, 0);
      __builtin_amdgcn_global_load_lds((gptr_t)(const void*)gb,
                                       (lptr_t)(void*)&BsF[(w * 32 + t * 16) * 64],
                                       16, 0, 0);
    }
    __syncthreads();

    i8v af[2], bf[2];
#pragma unroll
    for (int mi = 0; mi < 2; mi++) {
      const int ar = (w >> 1) * 64 + mi * 32 + l31;
      const int sw = (ar >> 1) & 3;
      const int4 q0 = *(const int4*)&AsF[ar * 64 + ((2 * kb + 0) ^ sw) * 16];
      const int4 q1 = *(const int4*)&AsF[ar * 64 + ((2 * kb + 1) ^ sw) * 16];
      af[mi] = make_i8v(q0, q1);
    }
#pragma unroll
    for (int nj = 0; nj < 2; nj++) {
      const int br = (w & 1) * 64 + nj * 32 + l31;
      const int sw = (br >> 1) & 3;
      const int4 q0 = *(const int4*)&BsF[br * 64 + ((2 * kb + 0) ^ sw) * 16];
      const int4 q1 = *(const int4*)&BsF[br * 64 + ((2 * kb + 1) ^ sw) * 16];
      bf[nj] = make_i8v(q0, q1);
    }
#pragma unroll
    for (int mi = 0; mi < 2; mi++)
#pragma unroll
      for (int nj = 0; nj < 2; nj++)
        acc[mi][nj] = __builtin_amdgcn_mfma_scale_f32_32x32x64_f8f6f4(
            af[mi], bf[nj], acc[mi][nj], 0 /*cbsz: fp8*/, 0 /*blgp: fp8*/,
            0, SCALE_1_16, 0, SCALE_1_16);
  }

  // Epilogue: d = exp(s)-1 -> Pd (e4m3, x128) + LDS partial row sums of d.
  // 32x32 C layout: row = (reg&3) + 8*(reg>>2) + 4*(lane>>5), col = lane&31.
  const int mbase = (w >> 1) * 64;
  const int nbase = (w & 1) * 64;
  const int rowoff = 4 * (lane >> 5);
  const int cslot = (w & 1) * 32 + l31;  // column slot: wave n-half x lane
#pragma unroll
  for (int mi = 0; mi < 2; mi++)
#pragma unroll
    for (int r4 = 0; r4 < 4; r4++)
#pragma unroll
      for (int rr = 0; rr < 4; rr++) {
        const int reg = r4 * 4 + rr;
        const int rl = mbase + mi * 32 + rr + 8 * r4 + rowoff;
        const float p0 = __expf(acc[mi][0][reg]);
        const float p1 = __expf(acc[mi][1][reg]);
        const size_t base = (size_t)(i0 + rl) * NQ + j0 + nbase + l31;
        Pd[base]      = f2e4m3((p0 - 1.f) * 128.f);
        Pd[base + 32] = f2e4m3((p1 - 1.f) * 128.f);
        lsums[rl][cslot] = (p0 + p1) - 2.f;  // each (rl,cslot) written once
      }
  __syncthreads();
  if (tid < 128) {
    float s = 0.f;
#pragma unroll
    for (int c = 0; c < 64; c++) s += lsums[tid][c];
    atomicAdd(&lsum[i0 + tid], s);
  }
}

// ---------------------------------------------------------------------------
// Pass 2: out[i][n] = (colV[n] + sum_k d[i][k]*V[n][k]) / (8192 + lsum[i]).
// Exact clone of qk_fp8's proven MX loop: A = Pd (scale 2^-7), B = supT8
// (scale 2^0), K = 8192.  LDS traffic per block-K-step: 48 KB (vs 96 KB in
// the bf16 pv) and MFMA at 2x bf16 rate -> attacks the measured LDS-BW bound.
// Grid (8 n-tiles, 64 i-tiles): XCD = flat%8 = n-tile -> each XCD's L2 holds
// one 1 MB V8 panel; Pd streams through L3 (64 MB).
// ---------------------------------------------------------------------------
__global__ __launch_bounds__(256, 2)
void pv_fp8(const unsigned char* __restrict__ Pd,    // [8192][8192] e4m3
            const unsigned char* __restrict__ V8,    // [1024][8192] e4m3
            const float* __restrict__ lsum,          // [8192] = sum(p-1)
            const float* __restrict__ colV,          // [1024] = sum_j V[n][j]
            float* __restrict__ out) {               // [8192][1024] fp32
  __shared__ __align__(16) unsigned char AsF[128 * 64];
  __shared__ __align__(16) unsigned char BsF[128 * 64];
  const int tid = threadIdx.x;
  const int lane = tid & 63;
  const int w = tid >> 6;
  const int i0 = blockIdx.y * 128;
  const int n0 = blockIdx.x * 128;

  f32x16 acc[2][2];
#pragma unroll
  for (int a = 0; a < 2; a++)
#pragma unroll
    for (int b = 0; b < 2; b++)
#pragma unroll
      for (int r = 0; r < 16; r++) acc[a][b][r] = 0.f;

  const int srow = lane >> 2;
  const int slot = lane & 3;
  const int kb = lane >> 5;
  const int l31 = lane & 31;

  for (int kk = 0; kk < NQ; kk += 64) {
    __syncthreads();
#pragma unroll
    for (int t = 0; t < 2; t++) {
      const int r = w * 32 + t * 16 + srow;
      const int c = slot ^ ((r >> 1) & 3);
      const unsigned char* ga = &Pd[(size_t)(i0 + r) * NQ + kk + c * 16];
      const unsigned char* gb = &V8[(size_t)(n0 + r) * NQ + kk + c * 16];
      __builtin_amdgcn_global_load_lds((gptr_t)(const void*)ga,
                                       (lptr_t)(void*)&AsF[(w * 32 + t * 16) * 64],
                                       16, 0, 0);
      __builtin_amdgcn_global_load_lds((gptr_t)(const void*)gb,
                                       (lptr_t)(void*)&BsF[(w * 32 + t * 16) * 64],
                                       16, 0, 0);
    }
    __syncthreads();

    i8v af[2], bf[2];
#pragma unroll
    for (int mi = 0; mi < 2; mi++) {
      const int ar = (w >> 1) * 64 + mi * 32 + l31;
      const int sw = (ar >> 1) & 3;
      const int4 q0 = *(const int4*)&AsF[ar * 64 + ((2 * kb + 0) ^ sw) * 16];
      const int4 q1 = *(const int4*)&AsF[ar * 64 + ((2 * kb + 1) ^ sw) * 16];
      af[mi] = make_i8v(q0, q1);
    }
#pragma unroll
    for (int nj = 0; nj < 2; nj++) {
      const int br = (w & 1) * 64 + nj * 32 + l31;
      const int sw = (br >> 1) & 3;
      const int4 q0 = *(const int4*)&BsF[br * 64 + ((2 * kb + 0) ^ sw) * 16];
      const int4 q1 = *(const int4*)&BsF[br * 64 + ((2 * kb + 1) ^ sw) * 16];
      bf[nj] = make_i8v(q0, q1);
    }
#pragma unroll
    for (int mi = 0; mi < 2; mi++)
#pragma unroll
      for (int nj = 0; nj < 2; nj++)
        acc[mi][nj] = __builtin_amdgcn_mfma_scale_f32_32x32x64_f8f6f4(
            af[mi], bf[nj], acc[mi][nj], 0 /*cbsz: fp8*/, 0 /*blgp: fp8*/,
            0, SCALE_1_128, 0, SCALE_1);
  }

  // Epilogue: out = (colV + acc) / (8192 + lsum[row]).
  const int mbase = (w >> 1) * 64;
  const int nbase = (w & 1) * 64;
  const int rowoff = 4 * (lane >> 5);
  const int c0 = n0 + nbase + l31;
  const float cv0 = colV[c0];
  const float cv1 = colV[c0 + 32];
#pragma unroll
  for (int mi = 0; mi < 2; mi++)
#pragma unroll
    for (int r4 = 0; r4 < 4; r4++)
#pragma unroll
      for (int rr = 0; rr < 4; rr++) {
        const int reg = r4 * 4 + rr;
        const int rl = mbase + mi * 32 + rr + 8 * r4 + rowoff;
        const int row = i0 + rl;
        const float linv = 1.f / (8192.f + lsum[row]);
        out[(size_t)row * DD + c0]      = (cv0 + acc[mi][0][reg]) * linv;
        out[(size_t)row * DD + c0 + 32] = (cv1 + acc[mi][1][reg]) * linv;
      }
}

// ---------------------------------------------------------------------------
// Fallback fp32 path — only if ws_size is too small.
// ---------------------------------------------------------------------------
#define BM 64
#define BN 64
#define BK 16

__global__ __launch_bounds__(256, 4)
void gemm64(const float* __restrict__ A, const float* __restrict__ B,
            float* __restrict__ C, int M, int N, int K) {
  __shared__ __align__(16) float As[BK][BM + 4];
  __shared__ __align__(16) float Bs[BK][BN + 4];
  const int tid = threadIdx.x;
  const int tx = tid & 15;
  const int ty = tid >> 4;
  const int row0 = blockIdx.y * BM;
  const int col0 = blockIdx.x * BN;
  float acc[4][4] = {};
  for (int k0 = 0; k0 < K; k0 += BK) {
    {
      const int r = tid >> 2;
      const int c4 = (tid & 3) * 4;
      const float4 v = *(const float4*)&A[(size_t)(row0 + r) * K + k0 + c4];
      As[c4 + 0][r] = v.x; As[c4 + 1][r] = v.y;
      As[c4 + 2][r] = v.z; As[c4 + 3][r] = v.w;
    }
    {
      const int r = tid >> 4;
      const int c4 = (tid & 15) * 4;
      *(float4*)&Bs[r][c4] = *(const float4*)&B[(size_t)(k0 + r) * N + col0 + c4];
    }
    __syncthreads();
#pragma unroll
    for (int k = 0; k < BK; k++) {
      const float4 a = *(const float4*)&As[k][4 * ty];
      const float4 b = *(const float4*)&Bs[k][4 * tx];
      const float av[4] = {a.x, a.y, a.z, a.w};
      const float bv[4] = {b.x, b.y, b.z, b.w};
#pragma unroll
      for (int i = 0; i < 4; i++)
#pragma unroll
        for (int j = 0; j < 4; j++)
          acc[i][j] += av[i] * bv[j];
    }
    __syncthreads();
  }
#pragma unroll
  for (int i = 0; i < 4; i++) {
    float4 o = {acc[i][0], acc[i][1], acc[i][2], acc[i][3]};
    *(float4*)&C[(size_t)(row0 + 4 * ty + i) * N + col0 + 4 * tx] = o;
  }
}

#define IT 32
#define JT 128
#define KC 32
#define CC 128
#define NCH (DD / CC)

__global__ __launch_bounds__(256, 1)
void fused_attn(const float* __restrict__ xi, const float* __restrict__ sup,
                float* __restrict__ out) {
  __shared__ __align__(16) float XiI[KC][IT + 4];
  __shared__ __align__(16) float XiJ[KC][JT + 4];
  __shared__ __align__(16) float Ps[JT][IT + 4];
  __shared__ __align__(16) float Vs[JT][CC + 4];
  __shared__ float lsum[IT];
  const int tid = threadIdx.x;
  const int i0 = blockIdx.x * IT;
  const int ry = tid >> 5;
  const int cx = tid & 31;
  if (tid < IT) lsum[tid] = 0.f;
  float oacc[NCH][4][4];
#pragma unroll
  for (int ch = 0; ch < NCH; ch++)
#pragma unroll
    for (int i = 0; i < 4; i++)
#pragma unroll
      for (int j = 0; j < 4; j++) oacc[ch][i][j] = 0.f;
  for (int j0 = 0; j0 < NQ; j0 += JT) {
    float sacc[4][4] = {};
    for (int kc = 0; kc < DD; kc += KC) {
      __syncthreads();
      {
        const int r = tid >> 3;
        const int k4 = (tid & 7) * 4;
        const float4 v = *(const float4*)&xi[(size_t)(i0 + r) * DD + kc + k4];
        XiI[k4 + 0][r] = v.x; XiI[k4 + 1][r] = v.y;
        XiI[k4 + 2][r] = v.z; XiI[k4 + 3][r] = v.w;
      }
#pragma unroll
      for (int i = 0; i < 4; i++) {
        const int idx = tid + i * 256;
        const int r = idx >> 3;
        const int k4 = (idx & 7) * 4;
        const float4 v = *(const float4*)&xi[(size_t)(j0 + r) * DD + kc + k4];
        XiJ[k4 + 0][r] = v.x; XiJ[k4 + 1][r] = v.y;
        XiJ[k4 + 2][r] = v.z; XiJ[k4 + 3][r] = v.w;
      }
      __syncthreads();
#pragma unroll
      for (int k = 0; k < KC; k++) {
        const float4 a = *(const float4*)&XiI[k][4 * ry];
        const float4 b = *(const float4*)&XiJ[k][4 * cx];
        const float av[4] = {a.x, a.y, a.z, a.w};
        const float bv[4] = {b.x, b.y, b.z, b.w};
#pragma unroll
        for (int i = 0; i < 4; i++)
#pragma unroll
          for (int j = 0; j < 4; j++)
            sacc[i][j] += av[i] * bv[j];
      }
    }
    __syncthreads();
    float rsv[4] = {0.f, 0.f, 0.f, 0.f};
#pragma unroll
    for (int i = 0; i < 4; i++)
#pragma unroll
      for (int j = 0; j < 4; j++) {
        const float p = __expf(sacc[i][j]);
        Ps[4 * cx + j][4 * ry + i] = p;
        rsv[i] += p;
      }
#pragma unroll
    for (int m = 16; m >= 1; m >>= 1)
#pragma unroll
      for (int i = 0; i < 4; i++) rsv[i] += __shfl_xor(rsv[i], m);
    if (cx == 0) {
#pragma unroll
      for (int i = 0; i < 4; i++) lsum[4 * ry + i] += rsv[i];
    }
    for (int ch = 0; ch < NCH; ch++) {
      __syncthreads();
#pragma unroll
      for (int i = 0; i < 16; i++) {
        const int idx = tid + i * 256;
        const int r = idx >> 5;
        const int c4 = (idx & 31) * 4;
        *(float4*)&Vs[r][c4] =
            *(const float4*)&sup[(size_t)(j0 + r) * DD + ch * CC + c4];
      }
      __syncthreads();
#pragma unroll 4
      for (int jp = 0; jp < JT; jp++) {
        const float4 p = *(const float4*)&Ps[jp][4 * ry];
        const float4 v = *(const float4*)&Vs[jp][4 * cx];
        const float pvv[4] = {p.x, p.y, p.z, p.w};
        const float vv[4] = {v.x, v.y, v.z, v.w};
#pragma unroll
        for (int i = 0; i < 4; i++)
#pragma unroll
          for (int j = 0; j < 4; j++)
            oacc[ch][i][j] += pvv[i] * vv[j];
      }
    }
  }
  __syncthreads();
  float linv[4];
#pragma unroll
  for (int i = 0; i < 4; i++) linv[i] = 1.f / lsum[4 * ry + i];
#pragma unroll
  for (int ch = 0; ch < NCH; ch++)
#pragma unroll
    for (int i = 0; i < 4; i++) {
      float4 o = {oacc[ch][i][0] * linv[i], oacc[ch][i][1] * linv[i],
                  oacc[ch][i][2] * linv[i], oacc[ch][i][3] * linv[i]};
      *(float4*)&out[(size_t)(i0 + 4 * ry + i) * DD + ch * CC + 4 * cx] = o;
    }
}

// ---------------------------------------------------------------------------
// Launch. ws layout (MFMA path, NEED = 152 MB + 32 KB):
//   Pd    : [0, 64MB)    e4m3 [8192][8192] = 128*(exp(s)-1)
//   supT8 : [64, 72MB)   e4m3 [1024][8192]
//   colV  : [72MB, +4KB) fp32 [1024]
//   xif   : [128,136MB)  e4m3 [8192][1024] (= fp8(16*xi))
//   supT  : [136,152MB)  bf16 [1024][8192] (for exact colV)
//   lsum  : [152MB,+32KB) fp32 [8192] = sum_j (p-1)  (zeroed, qk atomics)
//   transients (consumed before Pd is written, alias the Pd region):
//     xb [0,16MB) bf16 [8192][1024];  tiT [16,18MB);  wT [18,20MB)
// NOTE: reference uses transferi for BOTH projections; transferj unused.
// ---------------------------------------------------------------------------
extern "C" void kernel_launch(void* const* d_in, const int* in_sizes, int n_in,
                              void* d_out, int out_size, void* d_ws, size_t ws_size,
                              hipStream_t stream) {
  const float* x  = (const float*)d_in[0];
  const float* wt = (const float*)d_in[1];
  const float* ti = (const float*)d_in[2];
  float* out = (float*)d_out;

  char* ws = (char*)d_ws;
  const size_t MB = 1024 * 1024;
  const size_t NEED = 152 * MB + NQ * sizeof(float);

  if (ws_size >= NEED) {
    unsigned char*  Pd    = (unsigned char*)ws;
    unsigned char*  supT8 = (unsigned char*)(ws + 64 * MB);
    float*          colV  = (float*)(ws + 72 * MB);
    unsigned char*  xif   = (unsigned char*)(ws + 128 * MB);
    unsigned short* supT  = (unsigned short*)(ws + 136 * MB);
    float*          lsum  = (float*)(ws + 152 * MB);
    unsigned short* xb    = (unsigned short*)ws;             // transient in Pd
    unsigned short* tiT   = (unsigned short*)(ws + 16 * MB); // transient in Pd
    unsigned short* wT    = (unsigned short*)(ws + 18 * MB); // transient in Pd

    const int n4 = NQ * DD / 4;
    zero_f32<<<NQ / 256, 256, 0, stream>>>(lsum, NQ);
    f32_to_bf16<<<(n4 + 255) / 256, 256, 0, stream>>>(x, xb, n4);
    transpose_cvt<<<dim3(32, 32), 256, 0, stream>>>(ti, tiT, DD, DD);
    transpose_cvt<<<dim3(32, 32), 256, 0, stream>>>(wt, wT, DD, DD);

    // xif[m][n] = e4m3(16 * sum_k xb[m][k]*ti[k][n])
    proj_gemm<DD, 1><<<dim3(DD / 128, NQ / 128), 256, 0, stream>>>(
        xb, tiT, xif, nullptr);
    // supT[n][m] = bf16(sum_k W[k][n]*x[m][k]); supT8 = e4m3(same)
    proj_gemm<NQ, 2><<<dim3(NQ / 128, DD / 128), 256, 0, stream>>>(
        wT, xb, supT, supT8);
    // colV[n] = sum_j supT[n][j]  (exact bf16 base term)
    colsum_bf16<<<DD, 256, 0, stream>>>(supT, colV);

    qk_fp8<<<dim3(NQ / 128, NQ / 128), 256, 0, stream>>>(xif, Pd, lsum);
    pv_fp8<<<dim3(DD / 128, NQ / 128), 256, 0, stream>>>(Pd, supT8, lsum,
                                                         colV, out);
  } else {
    float* xi32  = (float*)ws;
    float* sup32 = (float*)(ws + 32 * MB);
    dim3 ggrid(DD / BN, NQ / BM);
    gemm64<<<ggrid, 256, 0, stream>>>(x, ti, xi32, NQ, DD, DD);
    gemm64<<<ggrid, 256, 0, stream>>>(x, wt, sup32, NQ, DD, DD);
    fused_attn<<<NQ / IT, 256, 0, stream>>>(xi32, sup32, out);
  }
}

// Round 4
// 723.773 us; speedup vs baseline: 1.0413x; 1.0413x over previous
//
#include <hip/hip_runtime.h>
#include <hip/hip_bf16.h>
#include <cstddef>

// Problem constants (match reference).
#define NQ 8192
#define DD 1024

typedef __attribute__((ext_vector_type(8))) short s8v;     // 8 bf16 (4 VGPR)
typedef __attribute__((ext_vector_type(8))) int i8v;       // 32 fp8 bytes (8 VGPR)
typedef __attribute__((ext_vector_type(4))) float f32x4;   // 16x16 C/D frag
typedef __attribute__((ext_vector_type(16))) float f32x16; // 32x32 C/D frag

typedef const __attribute__((address_space(1))) unsigned int* gptr_t;
typedef __attribute__((address_space(3))) unsigned int* lptr_t;

#define SCALE_1_16 0x7B7B7B7Bu   // E8M0 123 = 2^-4 (qk: undo 16x pre-scale twice)
#define SCALE_1_128 0x78787878u  // E8M0 120 = 2^-7 (pv A: undo 128x d-scale)
#define SCALE_1    0x7F7F7F7Fu   // E8M0 127 = 2^0  (pv B)

__device__ inline unsigned short f2bf(float f) {
  union { float f; unsigned u; } v; v.f = f;
  unsigned r = (v.u + 0x7FFFu + ((v.u >> 16) & 1u)) >> 16;  // RNE
  return (unsigned short)r;
}
__device__ inline float bits2f(unsigned u) {
  union { unsigned u; float f; } v; v.u = u;
  return v.f;
}

// f32 -> OCP e4m3 bits, RNE, clamp to +-448.
__device__ inline unsigned char f2e4m3(float x) {
  union { float f; unsigned u; } v; v.f = x;
  const unsigned s = (v.u >> 31) << 7;
  unsigned au = v.u & 0x7FFFFFFFu;
  if (au > 0x43E00000u) au = 0x43E00000u;  // clamp |x| to 448.0
  if (au >= 0x3C800000u) {                 // |x| >= 2^-6: e4m3 normal
    const unsigned rounded = au + 0x7FFFFu + ((au >> 20) & 1u);  // RNE @ 3 mant
    const unsigned e8 = ((rounded >> 23) & 0xFF) - 120u;         // -127+7
    const unsigned m8 = (rounded >> 20) & 7u;
    return (unsigned char)(s | (e8 << 3) | m8);
  } else {                                 // subnormal
    union { unsigned u; float f; } a; a.u = au;
    const unsigned q = (unsigned)rintf(a.f * 512.0f);  // 0..8
    return (unsigned char)(s | q);
  }
}

// Register-only combine of two 16-B LDS loads into one fp8 MFMA operand.
__device__ inline i8v make_i8v(int4 a, int4 b) {
  i8v v;
  v[0] = a.x; v[1] = a.y; v[2] = a.z; v[3] = a.w;
  v[4] = b.x; v[5] = b.y; v[6] = b.z; v[7] = b.w;
  return v;
}

// ---------------------------------------------------------------------------
// m97-style bf16 MFMA main loop: C(128x128) += A(128xK) @ B(128xK)^T.
// XOR-swizzled 16-B chunks, 0 bank conflicts (verified round-0).
// ---------------------------------------------------------------------------
template <int KDIM, int ASTR, int BSTR>
__device__ inline void mfma_core(const unsigned short* __restrict__ A,
                                 const unsigned short* __restrict__ B,
                                 int i0, int j0, int tid,
                                 unsigned short* AsU, unsigned short* BsU,
                                 f32x4 (&acc)[4][4]) {
  const int lane = tid & 63;
  const int w = tid >> 6;
  const int wr = (w >> 1) * 64;
  const int wc = (w & 1) * 64;
  const int l16 = lane & 15;
  const int lq = lane >> 4;
  const int srow = lane >> 3;                          // 0..7
  const int scol = (((lane & 7) ^ (srow & 7)) * 8);    // swizzled 16-B chunk

  for (int kk = 0; kk < KDIM; kk += 64) {
    __syncthreads();
#pragma unroll
    for (int t = 0; t < 4; t++) {
      const int r0 = w * 32 + t * 8;
      const unsigned short* g = &A[(size_t)(i0 + r0 + srow) * ASTR + kk + scol];
      __builtin_amdgcn_global_load_lds((gptr_t)(const void*)g,
                                       (lptr_t)(void*)&AsU[r0 * 64], 16, 0, 0);
    }
#pragma unroll
    for (int t = 0; t < 4; t++) {
      const int r0 = w * 32 + t * 8;
      const unsigned short* g = &B[(size_t)(j0 + r0 + srow) * BSTR + kk + scol];
      __builtin_amdgcn_global_load_lds((gptr_t)(const void*)g,
                                       (lptr_t)(void*)&BsU[r0 * 64], 16, 0, 0);
    }
    __syncthreads();

    const int h = l16 & 7;
    s8v af[4][2], bf[4][2];
#pragma unroll
    for (int t = 0; t < 4; t++)
#pragma unroll
      for (int s = 0; s < 2; s++) {
        const int ch = ((s * 4 + lq) ^ h) * 8;  // swizzled chunk offset
        af[t][s] = *(const s8v*)&AsU[(wr + 16 * t + l16) * 64 + ch];
        bf[t][s] = *(const s8v*)&BsU[(wc + 16 * t + l16) * 64 + ch];
      }
#pragma unroll
    for (int s = 0; s < 2; s++)
#pragma unroll
      for (int a = 0; a < 4; a++)
#pragma unroll
        for (int b = 0; b < 4; b++)
          acc[a][b] = __builtin_amdgcn_mfma_f32_16x16x32_bf16(
              af[a][s], bf[b][s], acc[a][b], 0, 0, 0);
  }
}

// ---------------------------------------------------------------------------
// fp32 -> bf16 elementwise.
// ---------------------------------------------------------------------------
__global__ void f32_to_bf16(const float* __restrict__ in,
                            unsigned short* __restrict__ out, int n4) {
  int i = (blockIdx.x * blockDim.x + threadIdx.x);
  if (i < n4) {
    const float4 v = *(const float4*)&in[i * 4];
    ushort4 o;
    o.x = f2bf(v.x); o.y = f2bf(v.y); o.z = f2bf(v.z); o.w = f2bf(v.w);
    *(ushort4*)&out[i * 4] = o;
  }
}

__global__ void zero_f32(float* __restrict__ p, int n) {
  const int i = blockIdx.x * blockDim.x + threadIdx.x;
  if (i < n) p[i] = 0.f;
}

// ---------------------------------------------------------------------------
// fp32 [R][C] -> bf16 [C][R] transpose+convert (32x32 LDS tiles).
// ---------------------------------------------------------------------------
__global__ void transpose_cvt(const float* __restrict__ in,
                              unsigned short* __restrict__ out, int R, int C) {
  __shared__ float t[32][33];
  const int bx = blockIdx.x;
  const int by = blockIdx.y;
  const int x = threadIdx.x & 31;
  const int y = threadIdx.x >> 5;
#pragma unroll
  for (int i = 0; i < 32; i += 8)
    t[y + i][x] = in[(size_t)(by * 32 + y + i) * C + bx * 32 + x];
  __syncthreads();
#pragma unroll
  for (int i = 0; i < 32; i += 8)
    out[(size_t)(bx * 32 + y + i) * R + by * 32 + x] = f2bf(t[x][y + i]);
}

// ---------------------------------------------------------------------------
// Projection GEMM: C[m][n] = sum_k A[m][k] * BT[n][k], bf16 in, K=1024.
// OUTMODE 1: e4m3(16*v) only (xif).  OUTMODE 2: bf16 AND e4m3(v) (supT+supT8).
// fp8 outputs are staged in LDS (overlaid on the dead As buffer after a
// barrier) and written out as 128-B coalesced dwordx4 segments — round-3
// lesson: per-lane byte stores cost 18x write amplification (RMW sectors).
// ---------------------------------------------------------------------------
template <int NST, int OUTMODE>
__global__ __launch_bounds__(256, 2)
void proj_gemm(const unsigned short* __restrict__ A,
               const unsigned short* __restrict__ BT,
               void* __restrict__ C1, void* __restrict__ C2) {
  __shared__ __align__(16) unsigned short As[128 * 64];
  __shared__ __align__(16) unsigned short Bs[128 * 64];
  const int tid = threadIdx.x;
  const int m0 = blockIdx.y * 128;
  const int n0 = blockIdx.x * 128;

  f32x4 acc[4][4];
#pragma unroll
  for (int a = 0; a < 4; a++)
#pragma unroll
    for (int b = 0; b < 4; b++) acc[a][b] = (f32x4){0.f, 0.f, 0.f, 0.f};

  mfma_core<DD, DD, DD>(A, BT, m0, n0, tid, As, Bs, acc);

  const int lane = tid & 63;
  const int w = tid >> 6;
  const int wr = (w >> 1) * 64, wc = (w & 1) * 64;
  const int l16 = lane & 15, lq = lane >> 4;
  unsigned char* tile = (unsigned char*)As;  // 16 KB overlay (dead after sync)
  if (OUTMODE >= 1) __syncthreads();         // all waves done reading As/Bs
#pragma unroll
  for (int ti = 0; ti < 4; ti++)
#pragma unroll
    for (int r = 0; r < 4; r++) {
      const int row = wr + 16 * ti + lq * 4 + r;
#pragma unroll
      for (int tj = 0; tj < 4; tj++) {
        const int col = wc + 16 * tj + l16;
        const float v = acc[ti][tj][r];
        if (OUTMODE == 1) {
          tile[row * 128 + col] = f2e4m3(v * 16.f);
        } else if (OUTMODE == 2) {
          ((unsigned short*)C1)[(size_t)(m0 + row) * NST + n0 + col] = f2bf(v);
          tile[row * 128 + col] = f2e4m3(v);
        } else {
          ((unsigned short*)C1)[(size_t)(m0 + row) * NST + n0 + col] = f2bf(v);
        }
      }
    }
  if (OUTMODE >= 1) {
    __syncthreads();
    unsigned char* dst8 =
        (OUTMODE == 1) ? (unsigned char*)C1 : (unsigned char*)C2;
    const int rr2 = tid >> 3;       // 0..31: row within 32-row group
    const int ch = (tid & 7) * 16;  // 16-B chunk; 8 lanes = 128-B segment
#pragma unroll
    for (int q = 0; q < 4; q++) {
      const int row = rr2 + q * 32;
      const int4 vv = *(const int4*)&tile[row * 128 + ch];
      *(int4*)&dst8[(size_t)(m0 + row) * NST + n0 + ch] = vv;
    }
  }
}

// ---------------------------------------------------------------------------
// colV[n] = sum_j supT[n][j]  (bf16 input, exact fp32 accumulate).
// ---------------------------------------------------------------------------
__global__ __launch_bounds__(256, 4)
void colsum_bf16(const unsigned short* __restrict__ supT,
                 float* __restrict__ colV) {
  const int row = blockIdx.x;
  const int tid = threadIdx.x;
  const unsigned short* pr = &supT[(size_t)row * NQ];
  float s = 0.f;
#pragma unroll
  for (int i = 0; i < 4; i++) {
    const int4 q = *(const int4*)&pr[(size_t)(tid + i * 256) * 8];
    s += bits2f((unsigned)q.x << 16) + bits2f((unsigned)q.x & 0xFFFF0000u);
    s += bits2f((unsigned)q.y << 16) + bits2f((unsigned)q.y & 0xFFFF0000u);
    s += bits2f((unsigned)q.z << 16) + bits2f((unsigned)q.z & 0xFFFF0000u);
    s += bits2f((unsigned)q.w << 16) + bits2f((unsigned)q.w & 0xFFFF0000u);
  }
#pragma unroll
  for (int m = 32; m >= 1; m >>= 1) s += __shfl_xor(s, m);
  __shared__ float red[4];
  if ((tid & 63) == 0) red[tid >> 6] = s;
  __syncthreads();
  if (tid == 0) colV[row] = red[0] + red[1] + red[2] + red[3];
}

// ---------------------------------------------------------------------------
// Pass 1: Pd = e4m3(128*(exp(s)-1)) where s = xi @ xi^T, via MX fp8 MFMA.
// P = 1 + d decomposition: |s| <~ 0.2 off-diag (diag ~1.05), so d*128 fits
// e4m3 (<=238).  Pd write is staged in LDS (overlay on the dead staging
// buffers) and stored as 128-B coalesced segments — NOT per-lane byte
// stores (round-3: 18x write amplification).
// lsum accumulates sum_j (p-1) via padded-LDS partials + 1 atomicAdd/row.
// ---------------------------------------------------------------------------
__global__ __launch_bounds__(256, 3)
void qk_fp8(const unsigned char* __restrict__ xif,  // [8192][1024] e4m3(16*xi)
            unsigned char* __restrict__ Pd,         // [8192][8192] e4m3(128*d)
            float* __restrict__ lsum) {             // [8192] fp32 (pre-zeroed)
  __shared__ __align__(16) unsigned char smem[2 * 128 * 64];  // AsF|BsF / tile
  __shared__ float lsums[128][65];                  // padded, conflict-free
  unsigned char* AsF = smem;
  unsigned char* BsF = smem + 128 * 64;
  const int tid = threadIdx.x;
  const int lane = tid & 63;
  const int w = tid >> 6;
  const int i0 = blockIdx.y * 128;
  const int j0 = blockIdx.x * 128;

  f32x16 acc[2][2];
#pragma unroll
  for (int a = 0; a < 2; a++)
#pragma unroll
    for (int b = 0; b < 2; b++)
#pragma unroll
      for (int r = 0; r < 16; r++) acc[a][b][r] = 0.f;

  const int srow = lane >> 2;  // 0..15: row within 16-row staging group
  const int slot = lane & 3;   // 16-B chunk slot within the row
  const int kb = lane >> 5;    // frag k-block (0/1)
  const int l31 = lane & 31;

  for (int kk = 0; kk < DD; kk += 64) {
    __syncthreads();
#pragma unroll
    for (int t = 0; t < 2; t++) {
      const int r = w * 32 + t * 16 + srow;
      const int c = slot ^ ((r >> 1) & 3);  // logical chunk for this slot
      const unsigned char* ga = &xif[(size_t)(i0 + r) * DD + kk + c * 16];
      const unsigned char* gb = &xif[(size_t)(j0 + r) * DD + kk + c * 16];
      __builtin_amdgcn_global_load_lds((gptr_t)(const void*)ga,
                                       (lptr_t)(void*)&AsF[(w * 32 + t * 16) * 64],
                                       16, 0, 0);
      __builtin_amdgcn_global_load_lds((gptr_t)(const void*)gb,
                                       (lptr_t)(void*)&BsF[(w * 32 + t * 16) * 64],
                                       16, 0, 0);
    }
    __syncthreads();

    i8v af[2], bf[2];
#pragma unroll
    for (int mi = 0; mi < 2; mi++) {
      const int ar = (w >> 1) * 64 + mi * 32 + l31;
      const int sw = (ar >> 1) & 3;
      const int4 q0 = *(const int4*)&AsF[ar * 64 + ((2 * kb + 0) ^ sw) * 16];
      const int4 q1 = *(const int4*)&AsF[ar * 64 + ((2 * kb + 1) ^ sw) * 16];
      af[mi] = make_i8v(q0, q1);
    }
#pragma unroll
    for (int nj = 0; nj < 2; nj++) {
      const int br = (w & 1) * 64 + nj * 32 + l31;
      const int sw = (br >> 1) & 3;
      const int4 q0 = *(const int4*)&BsF[br * 64 + ((2 * kb + 0) ^ sw) * 16];
      const int4 q1 = *(const int4*)&BsF[br * 64 + ((2 * kb + 1) ^ sw) * 16];
      bf[nj] = make_i8v(q0, q1);
    }
#pragma unroll
    for (int mi = 0; mi < 2; mi++)
#pragma unroll
      for (int nj = 0; nj < 2; nj++)
        acc[mi][nj] = __builtin_amdgcn_mfma_scale_f32_32x32x64_f8f6f4(
            af[mi], bf[nj], acc[mi][nj], 0 /*cbsz: fp8*/, 0 /*blgp: fp8*/,
            0, SCALE_1_16, 0, SCALE_1_16);
  }

  // Epilogue: d = exp(s)-1 staged into the (now dead) 16 KB smem tile,
  // then coalesced 128-B write-out.  lsums via padded LDS as before.
  __syncthreads();  // all waves finished reading AsF/BsF
  unsigned char* tile = smem;  // [128][128] bytes
  const int mbase = (w >> 1) * 64;
  const int nbase = (w & 1) * 64;
  const int rowoff = 4 * (lane >> 5);
  const int cslot = (w & 1) * 32 + l31;  // column slot: wave n-half x lane
#pragma unroll
  for (int mi = 0; mi < 2; mi++)
#pragma unroll
    for (int r4 = 0; r4 < 4; r4++)
#pragma unroll
      for (int rr = 0; rr < 4; rr++) {
        const int reg = r4 * 4 + rr;
        const int rl = mbase + mi * 32 + rr + 8 * r4 + rowoff;
        const float p0 = __expf(acc[mi][0][reg]);
        const float p1 = __expf(acc[mi][1][reg]);
        tile[rl * 128 + nbase + l31]      = f2e4m3((p0 - 1.f) * 128.f);
        tile[rl * 128 + nbase + l31 + 32] = f2e4m3((p1 - 1.f) * 128.f);
        lsums[rl][cslot] = (p0 + p1) - 2.f;  // each (rl,cslot) written once
      }
  __syncthreads();
  {
    const int rr2 = tid >> 3;       // 0..31
    const int ch = (tid & 7) * 16;  // 8 lanes x 16 B = 128-B segment
#pragma unroll
    for (int q = 0; q < 4; q++) {
      const int row = rr2 + q * 32;
      const int4 vv = *(const int4*)&tile[row * 128 + ch];
      *(int4*)&Pd[(size_t)(i0 + row) * NQ + j0 + ch] = vv;
    }
  }
  if (tid < 128) {
    float s = 0.f;
#pragma unroll
    for (int c = 0; c < 64; c++) s += lsums[tid][c];
    atomicAdd(&lsum[i0 + tid], s);
  }
}

// ---------------------------------------------------------------------------
// Pass 2: out[i][n] = (colV[n] + sum_k d[i][k]*V[n][k]) / (8192 + lsum[i]).
// Clone of qk's MX loop: A = Pd (scale 2^-7), B = supT8 (scale 2^0), K=8192.
// LDS traffic per block-K-step: 48 KB (vs 96 KB bf16 pv) + 2x MFMA rate.
// Grid (8 n-tiles, 64 i-tiles): XCD = flat%8 = n-tile -> V8 panel L2-resident.
// out stores are fp32, 32 lanes x 4 B = 128-B segments (coalesced).
// ---------------------------------------------------------------------------
__global__ __launch_bounds__(256, 2)
void pv_fp8(const unsigned char* __restrict__ Pd,    // [8192][8192] e4m3
            const unsigned char* __restrict__ V8,    // [1024][8192] e4m3
            const float* __restrict__ lsum,          // [8192] = sum(p-1)
            const float* __restrict__ colV,          // [1024] = sum_j V[n][j]
            float* __restrict__ out) {               // [8192][1024] fp32
  __shared__ __align__(16) unsigned char AsF[128 * 64];
  __shared__ __align__(16) unsigned char BsF[128 * 64];
  const int tid = threadIdx.x;
  const int lane = tid & 63;
  const int w = tid >> 6;
  const int i0 = blockIdx.y * 128;
  const int n0 = blockIdx.x * 128;

  f32x16 acc[2][2];
#pragma unroll
  for (int a = 0; a < 2; a++)
#pragma unroll
    for (int b = 0; b < 2; b++)
#pragma unroll
      for (int r = 0; r < 16; r++) acc[a][b][r] = 0.f;

  const int srow = lane >> 2;
  const int slot = lane & 3;
  const int kb = lane >> 5;
  const int l31 = lane & 31;

  for (int kk = 0; kk < NQ; kk += 64) {
    __syncthreads();
#pragma unroll
    for (int t = 0; t < 2; t++) {
      const int r = w * 32 + t * 16 + srow;
      const int c = slot ^ ((r >> 1) & 3);
      const unsigned char* ga = &Pd[(size_t)(i0 + r) * NQ + kk + c * 16];
      const unsigned char* gb = &V8[(size_t)(n0 + r) * NQ + kk + c * 16];
      __builtin_amdgcn_global_load_lds((gptr_t)(const void*)ga,
                                       (lptr_t)(void*)&AsF[(w * 32 + t * 16) * 64],
                                       16, 0, 0);
      __builtin_amdgcn_global_load_lds((gptr_t)(const void*)gb,
                                       (lptr_t)(void*)&BsF[(w * 32 + t * 16) * 64],
                                       16, 0, 0);
    }
    __syncthreads();

    i8v af[2], bf[2];
#pragma unroll
    for (int mi = 0; mi < 2; mi++) {
      const int ar = (w >> 1) * 64 + mi * 32 + l31;
      const int sw = (ar >> 1) & 3;
      const int4 q0 = *(const int4*)&AsF[ar * 64 + ((2 * kb + 0) ^ sw) * 16];
      const int4 q1 = *(const int4*)&AsF[ar * 64 + ((2 * kb + 1) ^ sw) * 16];
      af[mi] = make_i8v(q0, q1);
    }
#pragma unroll
    for (int nj = 0; nj < 2; nj++) {
      const int br = (w & 1) * 64 + nj * 32 + l31;
      const int sw = (br >> 1) & 3;
      const int4 q0 = *(const int4*)&BsF[br * 64 + ((2 * kb + 0) ^ sw) * 16];
      const int4 q1 = *(const int4*)&BsF[br * 64 + ((2 * kb + 1) ^ sw) * 16];
      bf[nj] = make_i8v(q0, q1);
    }
#pragma unroll
    for (int mi = 0; mi < 2; mi++)
#pragma unroll
      for (int nj = 0; nj < 2; nj++)
        acc[mi][nj] = __builtin_amdgcn_mfma_scale_f32_32x32x64_f8f6f4(
            af[mi], bf[nj], acc[mi][nj], 0 /*cbsz: fp8*/, 0 /*blgp: fp8*/,
            0, SCALE_1_128, 0, SCALE_1);
  }

  // Epilogue: out = (colV + acc) / (8192 + lsum[row]).
  const int mbase = (w >> 1) * 64;
  const int nbase = (w & 1) * 64;
  const int rowoff = 4 * (lane >> 5);
  const int c0 = n0 + nbase + l31;
  const float cv0 = colV[c0];
  const float cv1 = colV[c0 + 32];
#pragma unroll
  for (int mi = 0; mi < 2; mi++)
#pragma unroll
    for (int r4 = 0; r4 < 4; r4++)
#pragma unroll
      for (int rr = 0; rr < 4; rr++) {
        const int reg = r4 * 4 + rr;
        const int rl = mbase + mi * 32 + rr + 8 * r4 + rowoff;
        const int row = i0 + rl;
        const float linv = 1.f / (8192.f + lsum[row]);
        out[(size_t)row * DD + c0]      = (cv0 + acc[mi][0][reg]) * linv;
        out[(size_t)row * DD + c0 + 32] = (cv1 + acc[mi][1][reg]) * linv;
      }
}

// ---------------------------------------------------------------------------
// Fallback fp32 path — only if ws_size is too small.
// ---------------------------------------------------------------------------
#define BM 64
#define BN 64
#define BK 16

__global__ __launch_bounds__(256, 4)
void gemm64(const float* __restrict__ A, const float* __restrict__ B,
            float* __restrict__ C, int M, int N, int K) {
  __shared__ __align__(16) float As[BK][BM + 4];
  __shared__ __align__(16) float Bs[BK][BN + 4];
  const int tid = threadIdx.x;
  const int tx = tid & 15;
  const int ty = tid >> 4;
  const int row0 = blockIdx.y * BM;
  const int col0 = blockIdx.x * BN;
  float acc[4][4] = {};
  for (int k0 = 0; k0 < K; k0 += BK) {
    {
      const int r = tid >> 2;
      const int c4 = (tid & 3) * 4;
      const float4 v = *(const float4*)&A[(size_t)(row0 + r) * K + k0 + c4];
      As[c4 + 0][r] = v.x; As[c4 + 1][r] = v.y;
      As[c4 + 2][r] = v.z; As[c4 + 3][r] = v.w;
    }
    {
      const int r = tid >> 4;
      const int c4 = (tid & 15) * 4;
      *(float4*)&Bs[r][c4] = *(const float4*)&B[(size_t)(k0 + r) * N + col0 + c4];
    }
    __syncthreads();
#pragma unroll
    for (int k = 0; k < BK; k++) {
      const float4 a = *(const float4*)&As[k][4 * ty];
      const float4 b = *(const float4*)&Bs[k][4 * tx];
      const float av[4] = {a.x, a.y, a.z, a.w};
      const float bv[4] = {b.x, b.y, b.z, b.w};
#pragma unroll
      for (int i = 0; i < 4; i++)
#pragma unroll
        for (int j = 0; j < 4; j++)
          acc[i][j] += av[i] * bv[j];
    }
    __syncthreads();
  }
#pragma unroll
  for (int i = 0; i < 4; i++) {
    float4 o = {acc[i][0], acc[i][1], acc[i][2], acc[i][3]};
    *(float4*)&C[(size_t)(row0 + 4 * ty + i) * N + col0 + 4 * tx] = o;
  }
}

#define IT 32
#define JT 128
#define KC 32
#define CC 128
#define NCH (DD / CC)

__global__ __launch_bounds__(256, 1)
void fused_attn(const float* __restrict__ xi, const float* __restrict__ sup,
                float* __restrict__ out) {
  __shared__ __align__(16) float XiI[KC][IT + 4];
  __shared__ __align__(16) float XiJ[KC][JT + 4];
  __shared__ __align__(16) float Ps[JT][IT + 4];
  __shared__ __align__(16) float Vs[JT][CC + 4];
  __shared__ float lsum[IT];
  const int tid = threadIdx.x;
  const int i0 = blockIdx.x * IT;
  const int ry = tid >> 5;
  const int cx = tid & 31;
  if (tid < IT) lsum[tid] = 0.f;
  float oacc[NCH][4][4];
#pragma unroll
  for (int ch = 0; ch < NCH; ch++)
#pragma unroll
    for (int i = 0; i < 4; i++)
#pragma unroll
      for (int j = 0; j < 4; j++) oacc[ch][i][j] = 0.f;
  for (int j0 = 0; j0 < NQ; j0 += JT) {
    float sacc[4][4] = {};
    for (int kc = 0; kc < DD; kc += KC) {
      __syncthreads();
      {
        const int r = tid >> 3;
        const int k4 = (tid & 7) * 4;
        const float4 v = *(const float4*)&xi[(size_t)(i0 + r) * DD + kc + k4];
        XiI[k4 + 0][r] = v.x; XiI[k4 + 1][r] = v.y;
        XiI[k4 + 2][r] = v.z; XiI[k4 + 3][r] = v.w;
      }
#pragma unroll
      for (int i = 0; i < 4; i++) {
        const int idx = tid + i * 256;
        const int r = idx >> 3;
        const int k4 = (idx & 7) * 4;
        const float4 v = *(const float4*)&xi[(size_t)(j0 + r) * DD + kc + k4];
        XiJ[k4 + 0][r] = v.x; XiJ[k4 + 1][r] = v.y;
        XiJ[k4 + 2][r] = v.z; XiJ[k4 + 3][r] = v.w;
      }
      __syncthreads();
#pragma unroll
      for (int k = 0; k < KC; k++) {
        const float4 a = *(const float4*)&XiI[k][4 * ry];
        const float4 b = *(const float4*)&XiJ[k][4 * cx];
        const float av[4] = {a.x, a.y, a.z, a.w};
        const float bv[4] = {b.x, b.y, b.z, b.w};
#pragma unroll
        for (int i = 0; i < 4; i++)
#pragma unroll
          for (int j = 0; j < 4; j++)
            sacc[i][j] += av[i] * bv[j];
      }
    }
    __syncthreads();
    float rsv[4] = {0.f, 0.f, 0.f, 0.f};
#pragma unroll
    for (int i = 0; i < 4; i++)
#pragma unroll
      for (int j = 0; j < 4; j++) {
        const float p = __expf(sacc[i][j]);
        Ps[4 * cx + j][4 * ry + i] = p;
        rsv[i] += p;
      }
#pragma unroll
    for (int m = 16; m >= 1; m >>= 1)
#pragma unroll
      for (int i = 0; i < 4; i++) rsv[i] += __shfl_xor(rsv[i], m);
    if (cx == 0) {
#pragma unroll
      for (int i = 0; i < 4; i++) lsum[4 * ry + i] += rsv[i];
    }
    for (int ch = 0; ch < NCH; ch++) {
      __syncthreads();
#pragma unroll
      for (int i = 0; i < 16; i++) {
        const int idx = tid + i * 256;
        const int r = idx >> 5;
        const int c4 = (idx & 31) * 4;
        *(float4*)&Vs[r][c4] =
            *(const float4*)&sup[(size_t)(j0 + r) * DD + ch * CC + c4];
      }
      __syncthreads();
#pragma unroll 4
      for (int jp = 0; jp < JT; jp++) {
        const float4 p = *(const float4*)&Ps[jp][4 * ry];
        const float4 v = *(const float4*)&Vs[jp][4 * cx];
        const float pvv[4] = {p.x, p.y, p.z, p.w};
        const float vv[4] = {v.x, v.y, v.z, v.w};
#pragma unroll
        for (int i = 0; i < 4; i++)
#pragma unroll
          for (int j = 0; j < 4; j++)
            oacc[ch][i][j] += pvv[i] * vv[j];
      }
    }
  }
  __syncthreads();
  float linv[4];
#pragma unroll
  for (int i = 0; i < 4; i++) linv[i] = 1.f / lsum[4 * ry + i];
#pragma unroll
  for (int ch = 0; ch < NCH; ch++)
#pragma unroll
    for (int i = 0; i < 4; i++) {
      float4 o = {oacc[ch][i][0] * linv[i], oacc[ch][i][1] * linv[i],
                  oacc[ch][i][2] * linv[i], oacc[ch][i][3] * linv[i]};
      *(float4*)&out[(size_t)(i0 + 4 * ry + i) * DD + ch * CC + 4 * cx] = o;
    }
}

// ---------------------------------------------------------------------------
// Launch. ws layout (MFMA path, NEED = 152 MB + 32 KB):
//   Pd    : [0, 64MB)    e4m3 [8192][8192] = 128*(exp(s)-1)
//   supT8 : [64, 72MB)   e4m3 [1024][8192]
//   colV  : [72MB, +4KB) fp32 [1024]
//   xif   : [128,136MB)  e4m3 [8192][1024] (= fp8(16*xi))
//   supT  : [136,152MB)  bf16 [1024][8192] (for exact colV)
//   lsum  : [152MB,+32KB) fp32 [8192] = sum_j (p-1)  (zeroed, qk atomics)
//   transients (consumed before Pd is written, alias the Pd region):
//     xb [0,16MB) bf16 [8192][1024];  tiT [16,18MB);  wT [18,20MB)
// NOTE: reference uses transferi for BOTH projections; transferj unused.
// ---------------------------------------------------------------------------
extern "C" void kernel_launch(void* const* d_in, const int* in_sizes, int n_in,
                              void* d_out, int out_size, void* d_ws, size_t ws_size,
                              hipStream_t stream) {
  const float* x  = (const float*)d_in[0];
  const float* wt = (const float*)d_in[1];
  const float* ti = (const float*)d_in[2];
  float* out = (float*)d_out;

  char* ws = (char*)d_ws;
  const size_t MB = 1024 * 1024;
  const size_t NEED = 152 * MB + NQ * sizeof(float);

  if (ws_size >= NEED) {
    unsigned char*  Pd    = (unsigned char*)ws;
    unsigned char*  supT8 = (unsigned char*)(ws + 64 * MB);
    float*          colV  = (float*)(ws + 72 * MB);
    unsigned char*  xif   = (unsigned char*)(ws + 128 * MB);
    unsigned short* supT  = (unsigned short*)(ws + 136 * MB);
    float*          lsum  = (float*)(ws + 152 * MB);
    unsigned short* xb    = (unsigned short*)ws;             // transient in Pd
    unsigned short* tiT   = (unsigned short*)(ws + 16 * MB); // transient in Pd
    unsigned short* wT    = (unsigned short*)(ws + 18 * MB); // transient in Pd

    const int n4 = NQ * DD / 4;
    zero_f32<<<NQ / 256, 256, 0, stream>>>(lsum, NQ);
    f32_to_bf16<<<(n4 + 255) / 256, 256, 0, stream>>>(x, xb, n4);
    transpose_cvt<<<dim3(32, 32), 256, 0, stream>>>(ti, tiT, DD, DD);
    transpose_cvt<<<dim3(32, 32), 256, 0, stream>>>(wt, wT, DD, DD);

    // xif[m][n] = e4m3(16 * sum_k xb[m][k]*ti[k][n])
    proj_gemm<DD, 1><<<dim3(DD / 128, NQ / 128), 256, 0, stream>>>(
        xb, tiT, xif, nullptr);
    // supT[n][m] = bf16(sum_k W[k][n]*x[m][k]); supT8 = e4m3(same)
    proj_gemm<NQ, 2><<<dim3(NQ / 128, DD / 128), 256, 0, stream>>>(
        wT, xb, supT, supT8);
    // colV[n] = sum_j supT[n][j]  (exact bf16 base term)
    colsum_bf16<<<DD, 256, 0, stream>>>(supT, colV);

    qk_fp8<<<dim3(NQ / 128, NQ / 128), 256, 0, stream>>>(xif, Pd, lsum);
    pv_fp8<<<dim3(DD / 128, NQ / 128), 256, 0, stream>>>(Pd, supT8, lsum,
                                                         colV, out);
  } else {
    float* xi32  = (float*)ws;
    float* sup32 = (float*)(ws + 32 * MB);
    dim3 ggrid(DD / BN, NQ / BM);
    gemm64<<<ggrid, 256, 0, stream>>>(x, ti, xi32, NQ, DD, DD);
    gemm64<<<ggrid, 256, 0, stream>>>(x, wt, sup32, NQ, DD, DD);
    fused_attn<<<NQ / IT, 256, 0, stream>>>(xi32, sup32, out);
  }
}

// Round 5
// 436.267 us; speedup vs baseline: 1.7275x; 1.6590x over previous
//
#include <hip/hip_runtime.h>
#include <hip/hip_bf16.h>
#include <cstddef>

// Problem constants (match reference).
#define NQ 8192
#define DD 1024

typedef __attribute__((ext_vector_type(8))) short s8v;     // 8 bf16 (4 VGPR)
typedef __attribute__((ext_vector_type(8))) int i8v;       // 32 fp8 bytes (8 VGPR)
typedef __attribute__((ext_vector_type(4))) float f32x4;   // 16x16 C/D frag
typedef __attribute__((ext_vector_type(16))) float f32x16; // 32x32 C/D frag

typedef const __attribute__((address_space(1))) unsigned int* gptr_t;
typedef __attribute__((address_space(3))) unsigned int* lptr_t;

#define SCALE_1_16 0x7B7B7B7Bu  // E8M0 123 = 2^-4 in every byte

__device__ inline unsigned short f2bf(float f) {
  union { float f; unsigned u; } v; v.f = f;
  unsigned r = (v.u + 0x7FFFu + ((v.u >> 16) & 1u)) >> 16;  // RNE
  return (unsigned short)r;
}
__device__ inline float bits2f(unsigned u) {
  union { unsigned u; float f; } v; v.u = u;
  return v.f;
}

// f32 -> OCP e4m3 bits, RNE, clamp to +-448.
__device__ inline unsigned char f2e4m3(float x) {
  union { float f; unsigned u; } v; v.f = x;
  const unsigned s = (v.u >> 31) << 7;
  unsigned au = v.u & 0x7FFFFFFFu;
  if (au > 0x43E00000u) au = 0x43E00000u;  // clamp |x| to 448.0
  if (au >= 0x3C800000u) {                 // |x| >= 2^-6: e4m3 normal
    const unsigned rounded = au + 0x7FFFFu + ((au >> 20) & 1u);  // RNE @ 3 mant
    const unsigned e8 = ((rounded >> 23) & 0xFF) - 120u;         // -127+7
    const unsigned m8 = (rounded >> 20) & 7u;
    return (unsigned char)(s | (e8 << 3) | m8);
  } else {                                 // subnormal
    union { unsigned u; float f; } a; a.u = au;
    const unsigned q = (unsigned)rintf(a.f * 512.0f);  // 0..8
    return (unsigned char)(s | q);
  }
}

// Register-only combine of two 16-B LDS loads into one fp8 MFMA operand.
__device__ inline i8v make_i8v(int4 a, int4 b) {
  i8v v;
  v[0] = a.x; v[1] = a.y; v[2] = a.z; v[3] = a.w;
  v[4] = b.x; v[5] = b.y; v[6] = b.z; v[7] = b.w;
  return v;
}

// ---------------------------------------------------------------------------
// m97-style bf16 MFMA main loop: C(128x128) += A(128xK) @ B(128xK)^T.
// BK=64, global_load_lds dwordx4 staging, 4 waves, each 64x64 via 4x4 of
// 16x16x32 bf16 MFMA. Used by proj_gemm.
// LDS rows are 64 shorts = 128 B, 16-B chunks XOR-swizzled by row&7
// (global source column permuted; LDS dest linear).  0 bank conflicts
// (verified round-0).
// ---------------------------------------------------------------------------
template <int KDIM, int ASTR, int BSTR>
__device__ inline void mfma_core(const unsigned short* __restrict__ A,
                                 const unsigned short* __restrict__ B,
                                 int i0, int j0, int tid,
                                 unsigned short* AsU, unsigned short* BsU,
                                 f32x4 (&acc)[4][4]) {
  const int lane = tid & 63;
  const int w = tid >> 6;
  const int wr = (w >> 1) * 64;
  const int wc = (w & 1) * 64;
  const int l16 = lane & 15;
  const int lq = lane >> 4;
  const int srow = lane >> 3;                          // 0..7
  const int scol = (((lane & 7) ^ (srow & 7)) * 8);    // swizzled 16-B chunk

  for (int kk = 0; kk < KDIM; kk += 64) {
    __syncthreads();
#pragma unroll
    for (int t = 0; t < 4; t++) {
      const int r0 = w * 32 + t * 8;
      const unsigned short* g = &A[(size_t)(i0 + r0 + srow) * ASTR + kk + scol];
      __builtin_amdgcn_global_load_lds((gptr_t)(const void*)g,
                                       (lptr_t)(void*)&AsU[r0 * 64], 16, 0, 0);
    }
#pragma unroll
    for (int t = 0; t < 4; t++) {
      const int r0 = w * 32 + t * 8;
      const unsigned short* g = &B[(size_t)(j0 + r0 + srow) * BSTR + kk + scol];
      __builtin_amdgcn_global_load_lds((gptr_t)(const void*)g,
                                       (lptr_t)(void*)&BsU[r0 * 64], 16, 0, 0);
    }
    __syncthreads();

    const int h = l16 & 7;
    s8v af[4][2], bf[4][2];
#pragma unroll
    for (int t = 0; t < 4; t++)
#pragma unroll
      for (int s = 0; s < 2; s++) {
        const int ch = ((s * 4 + lq) ^ h) * 8;  // swizzled chunk offset
        af[t][s] = *(const s8v*)&AsU[(wr + 16 * t + l16) * 64 + ch];
        bf[t][s] = *(const s8v*)&BsU[(wc + 16 * t + l16) * 64 + ch];
      }
#pragma unroll
    for (int s = 0; s < 2; s++)
#pragma unroll
      for (int a = 0; a < 4; a++)
#pragma unroll
        for (int b = 0; b < 4; b++)
          acc[a][b] = __builtin_amdgcn_mfma_f32_16x16x32_bf16(
              af[a][s], bf[b][s], acc[a][b], 0, 0, 0);
  }
}

// ---------------------------------------------------------------------------
// fp32 -> bf16 elementwise.
// ---------------------------------------------------------------------------
__global__ void f32_to_bf16(const float* __restrict__ in,
                            unsigned short* __restrict__ out, int n4) {
  int i = (blockIdx.x * blockDim.x + threadIdx.x);
  if (i < n4) {
    const float4 v = *(const float4*)&in[i * 4];
    ushort4 o;
    o.x = f2bf(v.x); o.y = f2bf(v.y); o.z = f2bf(v.z); o.w = f2bf(v.w);
    *(ushort4*)&out[i * 4] = o;
  }
}

__global__ void zero_f32(float* __restrict__ p, int n) {
  const int i = blockIdx.x * blockDim.x + threadIdx.x;
  if (i < n) p[i] = 0.f;
}

// ---------------------------------------------------------------------------
// fp32 [R][C] -> bf16 [C][R] transpose+convert (32x32 LDS tiles).
// ---------------------------------------------------------------------------
__global__ void transpose_cvt(const float* __restrict__ in,
                              unsigned short* __restrict__ out, int R, int C) {
  __shared__ float t[32][33];
  const int bx = blockIdx.x;
  const int by = blockIdx.y;
  const int x = threadIdx.x & 31;
  const int y = threadIdx.x >> 5;
#pragma unroll
  for (int i = 0; i < 32; i += 8)
    t[y + i][x] = in[(size_t)(by * 32 + y + i) * C + bx * 32 + x];
  __syncthreads();
#pragma unroll
  for (int i = 0; i < 32; i += 8)
    out[(size_t)(bx * 32 + y + i) * R + by * 32 + x] = f2bf(t[x][y + i]);
}

// ---------------------------------------------------------------------------
// Projection GEMM: C[m][n] = sum_k A[m][k] * BT[n][k], bf16 in, K=1024.
// FP8OUT=true writes e4m3(16*value) for the MX qk pass (8 MB output — byte
// stores here were fine in rounds 0-2 empirically).
// ---------------------------------------------------------------------------
template <int NST, bool FP8OUT>
__global__ __launch_bounds__(256, 2)
void proj_gemm(const unsigned short* __restrict__ A,
               const unsigned short* __restrict__ BT,
               void* __restrict__ Cout) {
  __shared__ __align__(16) unsigned short As[128 * 64];
  __shared__ __align__(16) unsigned short Bs[128 * 64];
  const int tid = threadIdx.x;
  const int m0 = blockIdx.y * 128;
  const int n0 = blockIdx.x * 128;

  f32x4 acc[4][4];
#pragma unroll
  for (int a = 0; a < 4; a++)
#pragma unroll
    for (int b = 0; b < 4; b++) acc[a][b] = (f32x4){0.f, 0.f, 0.f, 0.f};

  mfma_core<DD, DD, DD>(A, BT, m0, n0, tid, As, Bs, acc);

  const int lane = tid & 63;
  const int w = tid >> 6;
  const int wr = (w >> 1) * 64, wc = (w & 1) * 64;
  const int l16 = lane & 15, lq = lane >> 4;
#pragma unroll
  for (int ti = 0; ti < 4; ti++)
#pragma unroll
    for (int r = 0; r < 4; r++) {
      const int row = m0 + wr + 16 * ti + lq * 4 + r;
#pragma unroll
      for (int tj = 0; tj < 4; tj++) {
        const int col = n0 + wc + 16 * tj + l16;
        if (FP8OUT) {
          ((unsigned char*)Cout)[(size_t)row * NST + col] =
              f2e4m3(acc[ti][tj][r] * 16.f);
        } else {
          ((unsigned short*)Cout)[(size_t)row * NST + col] = f2bf(acc[ti][tj][r]);
        }
      }
    }
}

// ---------------------------------------------------------------------------
// Pass 1: P = exp(xi @ xi^T) via MX-scaled fp8 MFMA (round-2 version, proven).
// xif holds e4m3(16*xi); both MFMA scales = 2^-4 undo the pre-scaling.
// 128x128 tile, 4 waves, each 64x64 = 2x2 of mfma_scale_f32_32x32x64_f8f6f4.
// Fused row sums: each lane writes its 32 per-row partials into padded LDS
// lsums[128][65], one sync, 128 threads sum 64 floats, 1 atomicAdd/row.
// P output stays bf16 (2-B stores) — fp8 P output measured 18x HBM write
// amplification in rounds 3-4 (mechanism unresolved; reverted on evidence).
// ---------------------------------------------------------------------------
__global__ __launch_bounds__(256, 3)
void qk_fp8(const unsigned char* __restrict__ xif,  // [8192][1024] e4m3(16*xi)
            unsigned short* __restrict__ P,         // [8192][8192] bf16 bits
            float* __restrict__ lsum) {             // [8192] fp32 (pre-zeroed)
  __shared__ __align__(16) unsigned char AsF[128 * 64];
  __shared__ __align__(16) unsigned char BsF[128 * 64];
  __shared__ float lsums[128][65];                  // padded, conflict-free
  const int tid = threadIdx.x;
  const int lane = tid & 63;
  const int w = tid >> 6;
  const int i0 = blockIdx.y * 128;
  const int j0 = blockIdx.x * 128;

  f32x16 acc[2][2];
#pragma unroll
  for (int a = 0; a < 2; a++)
#pragma unroll
    for (int b = 0; b < 2; b++)
#pragma unroll
      for (int r = 0; r < 16; r++) acc[a][b][r] = 0.f;

  const int srow = lane >> 2;  // 0..15: row within 16-row staging group
  const int slot = lane & 3;   // 16-B chunk slot within the row
  const int kb = lane >> 5;    // frag k-block (0/1)
  const int l31 = lane & 31;

  for (int kk = 0; kk < DD; kk += 64) {
    __syncthreads();
#pragma unroll
    for (int t = 0; t < 2; t++) {
      const int r = w * 32 + t * 16 + srow;
      const int c = slot ^ ((r >> 1) & 3);  // logical chunk for this slot
      const unsigned char* ga = &xif[(size_t)(i0 + r) * DD + kk + c * 16];
      const unsigned char* gb = &xif[(size_t)(j0 + r) * DD + kk + c * 16];
      __builtin_amdgcn_global_load_lds((gptr_t)(const void*)ga,
                                       (lptr_t)(void*)&AsF[(w * 32 + t * 16) * 64],
                                       16, 0, 0);
      __builtin_amdgcn_global_load_lds((gptr_t)(const void*)gb,
                                       (lptr_t)(void*)&BsF[(w * 32 + t * 16) * 64],
                                       16, 0, 0);
    }
    __syncthreads();

    i8v af[2], bf[2];
#pragma unroll
    for (int mi = 0; mi < 2; mi++) {
      const int ar = (w >> 1) * 64 + mi * 32 + l31;
      const int sw = (ar >> 1) & 3;
      const int4 q0 = *(const int4*)&AsF[ar * 64 + ((2 * kb + 0) ^ sw) * 16];
      const int4 q1 = *(const int4*)&AsF[ar * 64 + ((2 * kb + 1) ^ sw) * 16];
      af[mi] = make_i8v(q0, q1);
    }
#pragma unroll
    for (int nj = 0; nj < 2; nj++) {
      const int br = (w & 1) * 64 + nj * 32 + l31;
      const int sw = (br >> 1) & 3;
      const int4 q0 = *(const int4*)&BsF[br * 64 + ((2 * kb + 0) ^ sw) * 16];
      const int4 q1 = *(const int4*)&BsF[br * 64 + ((2 * kb + 1) ^ sw) * 16];
      bf[nj] = make_i8v(q0, q1);
    }
#pragma unroll
    for (int mi = 0; mi < 2; mi++)
#pragma unroll
      for (int nj = 0; nj < 2; nj++)
        acc[mi][nj] = __builtin_amdgcn_mfma_scale_f32_32x32x64_f8f6f4(
            af[mi], bf[nj], acc[mi][nj], 0 /*cbsz: fp8*/, 0 /*blgp: fp8*/,
            0, SCALE_1_16, 0, SCALE_1_16);
  }

  // Epilogue: p = exp(s) -> P (bf16) + LDS partial row sums.
  // 32x32 C layout: row = (reg&3) + 8*(reg>>2) + 4*(lane>>5), col = lane&31.
  const int mbase = (w >> 1) * 64;
  const int nbase = (w & 1) * 64;
  const int rowoff = 4 * (lane >> 5);
  const int cslot = (w & 1) * 32 + l31;  // column slot: wave n-half x lane
#pragma unroll
  for (int mi = 0; mi < 2; mi++)
#pragma unroll
    for (int r4 = 0; r4 < 4; r4++)
#pragma unroll
      for (int rr = 0; rr < 4; rr++) {
        const int reg = r4 * 4 + rr;
        const int rl = mbase + mi * 32 + rr + 8 * r4 + rowoff;
        const float p0 = __expf(acc[mi][0][reg]);
        const float p1 = __expf(acc[mi][1][reg]);
        const size_t base = (size_t)(i0 + rl) * NQ + j0 + nbase + l31;
        P[base]      = f2bf(p0);
        P[base + 32] = f2bf(p1);
        lsums[rl][cslot] = p0 + p1;  // each (rl,cslot) written exactly once
      }
  __syncthreads();
  if (tid < 128) {
    float s = 0.f;
#pragma unroll
    for (int c = 0; c < 64; c++) s += lsums[tid][c];
    atomicAdd(&lsum[i0 + tid], s);
  }
}

// ---------------------------------------------------------------------------
// Pass 2 (pv_fat): out = (P @ supT^T) / lsum[row], K = 8192 (bf16).
// Round-2 PMC showed pv is LDS-BW-bound (occupancy 21->34% left dur at 143us,
// MfmaUtil pinned ~42%).  Fix the BYTES/FLOP, not the schedule:
//   tile 256x128, 4 waves, wave w owns rows [w*64, w*64+64) x ALL 128 cols.
//   A-tile rows read ONCE (vs 2x), B-tile read 4x: LDS R+W per FLOP drops
//   1.33x (0.0458 -> 0.0343 KB/KFLOP).
// Grid 8x32 = 256 blocks = exactly 1/CU -> no cross-block latency hiding, so
// the staging is double-buffered (96 KB LDS): stage(next) issued BEFORE
// compute(cur); one vmcnt(0)+barrier per K-step (T3-minimum recipe).
// acc[4][8] = 128 regs; __launch_bounds__(256,1) (1 block/CU anyway).
// Same XOR swizzle as mfma_core (rows are 128 B).  XCD: flat%8 = n-tile.
// ---------------------------------------------------------------------------
__global__ __launch_bounds__(256, 1)
void pv_fat(const unsigned short* __restrict__ P,
            const unsigned short* __restrict__ supT,
            const float* __restrict__ lsum,
            float* __restrict__ out) {
  __shared__ __align__(16) unsigned short As[2][256 * 64];  // 64 KB
  __shared__ __align__(16) unsigned short Bs[2][128 * 64];  // 32 KB
  const int tid = threadIdx.x;
  const int lane = tid & 63;
  const int w = tid >> 6;  // 0..3
  const int l16 = lane & 15;
  const int lq = lane >> 4;
  const int srow = lane >> 3;                 // 0..7
  const int scol = ((lane & 7) ^ srow) * 8;   // swizzled 16-B chunk (shorts)
  const int i0 = blockIdx.y * 256;
  const int n0 = blockIdx.x * 128;

  f32x4 acc[4][8];
#pragma unroll
  for (int a = 0; a < 4; a++)
#pragma unroll
    for (int b = 0; b < 8; b++) acc[a][b] = (f32x4){0.f, 0.f, 0.f, 0.f};

  auto stage = [&](int buf, int t) {
    const int kk = t * 64;
#pragma unroll
    for (int q = 0; q < 8; q++) {  // A: wave w stages rows w*64 .. w*64+63
      const int r0 = w * 64 + q * 8;
      const unsigned short* g = &P[(size_t)(i0 + r0 + srow) * NQ + kk + scol];
      __builtin_amdgcn_global_load_lds((gptr_t)(const void*)g,
                                       (lptr_t)(void*)&As[buf][r0 * 64], 16, 0, 0);
    }
#pragma unroll
    for (int q = 0; q < 4; q++) {  // B: wave w stages rows w*32 .. w*32+31
      const int r0 = w * 32 + q * 8;
      const unsigned short* g = &supT[(size_t)(n0 + r0 + srow) * NQ + kk + scol];
      __builtin_amdgcn_global_load_lds((gptr_t)(const void*)g,
                                       (lptr_t)(void*)&Bs[buf][r0 * 64], 16, 0, 0);
    }
  };

  // Prologue: fill buffer 0.
  stage(0, 0);
  asm volatile("s_waitcnt vmcnt(0)" ::: "memory");
  __syncthreads();

  const int h = l16 & 7;
  int cur = 0;
#pragma unroll 1
  for (int t = 0; t < NQ / 64; t++) {
    if (t < NQ / 64 - 1) stage(cur ^ 1, t + 1);  // prefetch flies over compute
    const unsigned short* Ac = &As[cur][0];
    const unsigned short* Bc = &Bs[cur][0];
#pragma unroll
    for (int s = 0; s < 2; s++) {
      const int ch = ((s * 4 + lq) ^ h) * 8;  // swizzled chunk offset
      s8v af[4], bf[8];
#pragma unroll
      for (int a = 0; a < 4; a++)
        af[a] = *(const s8v*)&Ac[(w * 64 + 16 * a + l16) * 64 + ch];
#pragma unroll
      for (int b = 0; b < 8; b++)
        bf[b] = *(const s8v*)&Bc[(16 * b + l16) * 64 + ch];
#pragma unroll
      for (int a = 0; a < 4; a++)
#pragma unroll
        for (int b = 0; b < 8; b++)
          acc[a][b] = __builtin_amdgcn_mfma_f32_16x16x32_bf16(
              af[a], bf[b], acc[a][b], 0, 0, 0);
    }
    asm volatile("s_waitcnt vmcnt(0)" ::: "memory");  // next buffer landed
    __syncthreads();
    cur ^= 1;
  }

  // Epilogue: divide by row sum, store fp32 (64-B segments per 16 lanes).
#pragma unroll
  for (int a = 0; a < 4; a++)
#pragma unroll
    for (int r = 0; r < 4; r++) {
      const int row = i0 + w * 64 + 16 * a + lq * 4 + r;
      const float linv = 1.f / lsum[row];
#pragma unroll
      for (int b = 0; b < 8; b++) {
        const int col = n0 + 16 * b + l16;
        out[(size_t)row * DD + col] = acc[a][b][r] * linv;
      }
    }
}

// ---------------------------------------------------------------------------
// Fallback fp32 path — only if ws_size is too small.
// ---------------------------------------------------------------------------
#define BM 64
#define BN 64
#define BK 16

__global__ __launch_bounds__(256, 4)
void gemm64(const float* __restrict__ A, const float* __restrict__ B,
            float* __restrict__ C, int M, int N, int K) {
  __shared__ __align__(16) float As[BK][BM + 4];
  __shared__ __align__(16) float Bs[BK][BN + 4];
  const int tid = threadIdx.x;
  const int tx = tid & 15;
  const int ty = tid >> 4;
  const int row0 = blockIdx.y * BM;
  const int col0 = blockIdx.x * BN;
  float acc[4][4] = {};
  for (int k0 = 0; k0 < K; k0 += BK) {
    {
      const int r = tid >> 2;
      const int c4 = (tid & 3) * 4;
      const float4 v = *(const float4*)&A[(size_t)(row0 + r) * K + k0 + c4];
      As[c4 + 0][r] = v.x; As[c4 + 1][r] = v.y;
      As[c4 + 2][r] = v.z; As[c4 + 3][r] = v.w;
    }
    {
      const int r = tid >> 4;
      const int c4 = (tid & 15) * 4;
      *(float4*)&Bs[r][c4] = *(const float4*)&B[(size_t)(k0 + r) * N + col0 + c4];
    }
    __syncthreads();
#pragma unroll
    for (int k = 0; k < BK; k++) {
      const float4 a = *(const float4*)&As[k][4 * ty];
      const float4 b = *(const float4*)&Bs[k][4 * tx];
      const float av[4] = {a.x, a.y, a.z, a.w};
      const float bv[4] = {b.x, b.y, b.z, b.w};
#pragma unroll
      for (int i = 0; i < 4; i++)
#pragma unroll
        for (int j = 0; j < 4; j++)
          acc[i][j] += av[i] * bv[j];
    }
    __syncthreads();
  }
#pragma unroll
  for (int i = 0; i < 4; i++) {
    float4 o = {acc[i][0], acc[i][1], acc[i][2], acc[i][3]};
    *(float4*)&C[(size_t)(row0 + 4 * ty + i) * N + col0 + 4 * tx] = o;
  }
}

#define IT 32
#define JT 128
#define KC 32
#define CC 128
#define NCH (DD / CC)

__global__ __launch_bounds__(256, 1)
void fused_attn(const float* __restrict__ xi, const float* __restrict__ sup,
                float* __restrict__ out) {
  __shared__ __align__(16) float XiI[KC][IT + 4];
  __shared__ __align__(16) float XiJ[KC][JT + 4];
  __shared__ __align__(16) float Ps[JT][IT + 4];
  __shared__ __align__(16) float Vs[JT][CC + 4];
  __shared__ float lsum[IT];
  const int tid = threadIdx.x;
  const int i0 = blockIdx.x * IT;
  const int ry = tid >> 5;
  const int cx = tid & 31;
  if (tid < IT) lsum[tid] = 0.f;
  float oacc[NCH][4][4];
#pragma unroll
  for (int ch = 0; ch < NCH; ch++)
#pragma unroll
    for (int i = 0; i < 4; i++)
#pragma unroll
      for (int j = 0; j < 4; j++) oacc[ch][i][j] = 0.f;
  for (int j0 = 0; j0 < NQ; j0 += JT) {
    float sacc[4][4] = {};
    for (int kc = 0; kc < DD; kc += KC) {
      __syncthreads();
      {
        const int r = tid >> 3;
        const int k4 = (tid & 7) * 4;
        const float4 v = *(const float4*)&xi[(size_t)(i0 + r) * DD + kc + k4];
        XiI[k4 + 0][r] = v.x; XiI[k4 + 1][r] = v.y;
        XiI[k4 + 2][r] = v.z; XiI[k4 + 3][r] = v.w;
      }
#pragma unroll
      for (int i = 0; i < 4; i++) {
        const int idx = tid + i * 256;
        const int r = idx >> 3;
        const int k4 = (idx & 7) * 4;
        const float4 v = *(const float4*)&xi[(size_t)(j0 + r) * DD + kc + k4];
        XiJ[k4 + 0][r] = v.x; XiJ[k4 + 1][r] = v.y;
        XiJ[k4 + 2][r] = v.z; XiJ[k4 + 3][r] = v.w;
      }
      __syncthreads();
#pragma unroll
      for (int k = 0; k < KC; k++) {
        const float4 a = *(const float4*)&XiI[k][4 * ry];
        const float4 b = *(const float4*)&XiJ[k][4 * cx];
        const float av[4] = {a.x, a.y, a.z, a.w};
        const float bv[4] = {b.x, b.y, b.z, b.w};
#pragma unroll
        for (int i = 0; i < 4; i++)
#pragma unroll
          for (int j = 0; j < 4; j++)
            sacc[i][j] += av[i] * bv[j];
      }
    }
    __syncthreads();
    float rsv[4] = {0.f, 0.f, 0.f, 0.f};
#pragma unroll
    for (int i = 0; i < 4; i++)
#pragma unroll
      for (int j = 0; j < 4; j++) {
        const float p = __expf(sacc[i][j]);
        Ps[4 * cx + j][4 * ry + i] = p;
        rsv[i] += p;
      }
#pragma unroll
    for (int m = 16; m >= 1; m >>= 1)
#pragma unroll
      for (int i = 0; i < 4; i++) rsv[i] += __shfl_xor(rsv[i], m);
    if (cx == 0) {
#pragma unroll
      for (int i = 0; i < 4; i++) lsum[4 * ry + i] += rsv[i];
    }
    for (int ch = 0; ch < NCH; ch++) {
      __syncthreads();
#pragma unroll
      for (int i = 0; i < 16; i++) {
        const int idx = tid + i * 256;
        const int r = idx >> 5;
        const int c4 = (idx & 31) * 4;
        *(float4*)&Vs[r][c4] =
            *(const float4*)&sup[(size_t)(j0 + r) * DD + ch * CC + c4];
      }
      __syncthreads();
#pragma unroll 4
      for (int jp = 0; jp < JT; jp++) {
        const float4 p = *(const float4*)&Ps[jp][4 * ry];
        const float4 v = *(const float4*)&Vs[jp][4 * cx];
        const float pvv[4] = {p.x, p.y, p.z, p.w};
        const float vv[4] = {v.x, v.y, v.z, v.w};
#pragma unroll
        for (int i = 0; i < 4; i++)
#pragma unroll
          for (int j = 0; j < 4; j++)
            oacc[ch][i][j] += pvv[i] * vv[j];
      }
    }
  }
  __syncthreads();
  float linv[4];
#pragma unroll
  for (int i = 0; i < 4; i++) linv[i] = 1.f / lsum[4 * ry + i];
#pragma unroll
  for (int ch = 0; ch < NCH; ch++)
#pragma unroll
    for (int i = 0; i < 4; i++) {
      float4 o = {oacc[ch][i][0] * linv[i], oacc[ch][i][1] * linv[i],
                  oacc[ch][i][2] * linv[i], oacc[ch][i][3] * linv[i]};
      *(float4*)&out[(size_t)(i0 + 4 * ry + i) * DD + ch * CC + 4 * cx] = o;
    }
}

// ---------------------------------------------------------------------------
// Launch. ws layout (MFMA path, NEED = 152 MB + 32 KB):
//   P    : [0, 128MB)    bf16 [8192][8192]
//   xif  : [128,136MB)   e4m3 [8192][1024] (= fp8(16*xi))
//   supT : [136,152MB)   bf16 [1024][8192]
//   lsum : [152MB,+32KB) fp32 [8192]  (zeroed, filled by qk_fp8 atomics)
//   transients (consumed before P is written, alias the P region):
//     xb [0,16MB) bf16 [8192][1024];  tiT [16,18MB);  wT [18,20MB)
// NOTE: reference uses transferi for BOTH projections; transferj unused.
// ---------------------------------------------------------------------------
extern "C" void kernel_launch(void* const* d_in, const int* in_sizes, int n_in,
                              void* d_out, int out_size, void* d_ws, size_t ws_size,
                              hipStream_t stream) {
  const float* x  = (const float*)d_in[0];
  const float* wt = (const float*)d_in[1];
  const float* ti = (const float*)d_in[2];
  float* out = (float*)d_out;

  char* ws = (char*)d_ws;
  const size_t MB = 1024 * 1024;
  const size_t NEED = 152 * MB + NQ * sizeof(float);

  if (ws_size >= NEED) {
    unsigned short* P    = (unsigned short*)ws;
    unsigned char*  xif  = (unsigned char*)(ws + 128 * MB);
    unsigned short* supT = (unsigned short*)(ws + 136 * MB);
    float* lsum          = (float*)(ws + 152 * MB);
    unsigned short* xb   = (unsigned short*)ws;             // transient in P
    unsigned short* tiT  = (unsigned short*)(ws + 16 * MB); // transient in P
    unsigned short* wT   = (unsigned short*)(ws + 18 * MB); // transient in P

    const int n4 = NQ * DD / 4;
    zero_f32<<<NQ / 256, 256, 0, stream>>>(lsum, NQ);
    f32_to_bf16<<<(n4 + 255) / 256, 256, 0, stream>>>(x, xb, n4);
    transpose_cvt<<<dim3(32, 32), 256, 0, stream>>>(ti, tiT, DD, DD);
    transpose_cvt<<<dim3(32, 32), 256, 0, stream>>>(wt, wT, DD, DD);

    // xif[m][n] = e4m3(16 * sum_k xb[m][k]*ti[k][n])
    proj_gemm<DD, true><<<dim3(DD / 128, NQ / 128), 256, 0, stream>>>(xb, tiT, xif);
    // supT[n][m] = bf16(sum_k W[k][n]*x[m][k])
    proj_gemm<NQ, false><<<dim3(NQ / 128, DD / 128), 256, 0, stream>>>(wT, xb, supT);

    qk_fp8<<<dim3(NQ / 128, NQ / 128), 256, 0, stream>>>(xif, P, lsum);
    pv_fat<<<dim3(DD / 128, NQ / 256), 256, 0, stream>>>(P, supT, lsum, out);
  } else {
    float* xi32  = (float*)ws;
    float* sup32 = (float*)(ws + 32 * MB);
    dim3 ggrid(DD / BN, NQ / BM);
    gemm64<<<ggrid, 256, 0, stream>>>(x, ti, xi32, NQ, DD, DD);
    gemm64<<<ggrid, 256, 0, stream>>>(x, wt, sup32, NQ, DD, DD);
    fused_attn<<<NQ / IT, 256, 0, stream>>>(xi32, sup32, out);
  }
}

// Round 6
// 370.369 us; speedup vs baseline: 2.0349x; 1.1779x over previous
//
#include <hip/hip_runtime.h>
#include <hip/hip_bf16.h>
#include <cstddef>

// Problem constants (match reference).
#define NQ 8192
#define DD 1024

typedef __attribute__((ext_vector_type(8))) short s8v;     // 8 bf16 (4 VGPR)
typedef __attribute__((ext_vector_type(8))) int i8v;       // 32 fp8 bytes (8 VGPR)
typedef __attribute__((ext_vector_type(4))) float f32x4;   // 16x16 C/D frag
typedef __attribute__((ext_vector_type(16))) float f32x16; // 32x32 C/D frag

typedef const __attribute__((address_space(1))) unsigned int* gptr_t;
typedef __attribute__((address_space(3))) unsigned int* lptr_t;

#define SCALE_1_16 0x7B7B7B7Bu  // E8M0 123 = 2^-4 in every byte

__device__ inline unsigned short f2bf(float f) {
  union { float f; unsigned u; } v; v.f = f;
  unsigned r = (v.u + 0x7FFFu + ((v.u >> 16) & 1u)) >> 16;  // RNE
  return (unsigned short)r;
}
__device__ inline float bits2f(unsigned u) {
  union { unsigned u; float f; } v; v.u = u;
  return v.f;
}

// f32 -> OCP e4m3 bits, RNE, clamp to +-448.
__device__ inline unsigned char f2e4m3(float x) {
  union { float f; unsigned u; } v; v.f = x;
  const unsigned s = (v.u >> 31) << 7;
  unsigned au = v.u & 0x7FFFFFFFu;
  if (au > 0x43E00000u) au = 0x43E00000u;  // clamp |x| to 448.0
  if (au >= 0x3C800000u) {                 // |x| >= 2^-6: e4m3 normal
    const unsigned rounded = au + 0x7FFFFu + ((au >> 20) & 1u);  // RNE @ 3 mant
    const unsigned e8 = ((rounded >> 23) & 0xFF) - 120u;         // -127+7
    const unsigned m8 = (rounded >> 20) & 7u;
    return (unsigned char)(s | (e8 << 3) | m8);
  } else {                                 // subnormal
    union { unsigned u; float f; } a; a.u = au;
    const unsigned q = (unsigned)rintf(a.f * 512.0f);  // 0..8
    return (unsigned char)(s | q);
  }
}

// Register-only combine of two 16-B LDS loads into one fp8 MFMA operand.
__device__ inline i8v make_i8v(int4 a, int4 b) {
  i8v v;
  v[0] = a.x; v[1] = a.y; v[2] = a.z; v[3] = a.w;
  v[4] = b.x; v[5] = b.y; v[6] = b.z; v[7] = b.w;
  return v;
}

// ---------------------------------------------------------------------------
// Double-buffered m97-style bf16 MFMA loop: C(128x128) += A(128xK) @ B(128xK)^T.
// T3-minimum recipe: stage(t+1) is ISSUED before compute(t); one
// vmcnt(0)+barrier per K-step (drain is short because loads flew over the
// ds_read+MFMA phase).  Round-5's pv_fat proved the loop correct; here it is
// applied at the proven 128x128 / 2-blocks-per-CU geometry.
// XOR-swizzled 16-B chunks, 0 bank conflicts (verified round-0).
// ---------------------------------------------------------------------------
template <int KDIM, int ASTR, int BSTR>
__device__ inline void mfma_core_db(const unsigned short* __restrict__ A,
                                    const unsigned short* __restrict__ B,
                                    int i0, int j0, int tid,
                                    unsigned short* __restrict__ As0,
                                    unsigned short* __restrict__ As1,
                                    unsigned short* __restrict__ Bs0,
                                    unsigned short* __restrict__ Bs1,
                                    f32x4 (&acc)[4][4]) {
  const int lane = tid & 63;
  const int w = tid >> 6;
  const int wr = (w >> 1) * 64;
  const int wc = (w & 1) * 64;
  const int l16 = lane & 15;
  const int lq = lane >> 4;
  const int srow = lane >> 3;                          // 0..7
  const int scol = (((lane & 7) ^ (srow & 7)) * 8);    // swizzled 16-B chunk

  auto stage = [&](unsigned short* dA, unsigned short* dB, int kk) {
#pragma unroll
    for (int t = 0; t < 4; t++) {
      const int r0 = w * 32 + t * 8;
      const unsigned short* g = &A[(size_t)(i0 + r0 + srow) * ASTR + kk + scol];
      __builtin_amdgcn_global_load_lds((gptr_t)(const void*)g,
                                       (lptr_t)(void*)&dA[r0 * 64], 16, 0, 0);
    }
#pragma unroll
    for (int t = 0; t < 4; t++) {
      const int r0 = w * 32 + t * 8;
      const unsigned short* g = &B[(size_t)(j0 + r0 + srow) * BSTR + kk + scol];
      __builtin_amdgcn_global_load_lds((gptr_t)(const void*)g,
                                       (lptr_t)(void*)&dB[r0 * 64], 16, 0, 0);
    }
  };

  stage(As0, Bs0, 0);
  asm volatile("s_waitcnt vmcnt(0)" ::: "memory");
  __syncthreads();

  const int h = l16 & 7;
  unsigned short* curA = As0;
  unsigned short* curB = Bs0;
  unsigned short* nxtA = As1;
  unsigned short* nxtB = Bs1;
#pragma unroll 1
  for (int t = 0; t < KDIM / 64; t++) {
    if (t < KDIM / 64 - 1) stage(nxtA, nxtB, (t + 1) * 64);  // fly over compute
    s8v af[4][2], bf[4][2];
#pragma unroll
    for (int q = 0; q < 4; q++)
#pragma unroll
      for (int s = 0; s < 2; s++) {
        const int ch = ((s * 4 + lq) ^ h) * 8;  // swizzled chunk offset
        af[q][s] = *(const s8v*)&curA[(wr + 16 * q + l16) * 64 + ch];
        bf[q][s] = *(const s8v*)&curB[(wc + 16 * q + l16) * 64 + ch];
      }
#pragma unroll
    for (int s = 0; s < 2; s++)
#pragma unroll
      for (int a = 0; a < 4; a++)
#pragma unroll
        for (int b = 0; b < 4; b++)
          acc[a][b] = __builtin_amdgcn_mfma_f32_16x16x32_bf16(
              af[a][s], bf[b][s], acc[a][b], 0, 0, 0);
    asm volatile("s_waitcnt vmcnt(0)" ::: "memory");  // next buffer landed
    __syncthreads();
    unsigned short* tA = curA; curA = nxtA; nxtA = tA;
    unsigned short* tB = curB; curB = nxtB; nxtB = tB;
  }
}

// ---------------------------------------------------------------------------
// fp32 -> bf16 elementwise.
// ---------------------------------------------------------------------------
__global__ void f32_to_bf16(const float* __restrict__ in,
                            unsigned short* __restrict__ out, int n4) {
  int i = (blockIdx.x * blockDim.x + threadIdx.x);
  if (i < n4) {
    const float4 v = *(const float4*)&in[i * 4];
    ushort4 o;
    o.x = f2bf(v.x); o.y = f2bf(v.y); o.z = f2bf(v.z); o.w = f2bf(v.w);
    *(ushort4*)&out[i * 4] = o;
  }
}

__global__ void zero_f32(float* __restrict__ p, int n) {
  const int i = blockIdx.x * blockDim.x + threadIdx.x;
  if (i < n) p[i] = 0.f;
}

// ---------------------------------------------------------------------------
// fp32 [R][C] -> bf16 [C][R] transpose+convert (32x32 LDS tiles).
// ---------------------------------------------------------------------------
__global__ void transpose_cvt(const float* __restrict__ in,
                              unsigned short* __restrict__ out, int R, int C) {
  __shared__ float t[32][33];
  const int bx = blockIdx.x;
  const int by = blockIdx.y;
  const int x = threadIdx.x & 31;
  const int y = threadIdx.x >> 5;
#pragma unroll
  for (int i = 0; i < 32; i += 8)
    t[y + i][x] = in[(size_t)(by * 32 + y + i) * C + bx * 32 + x];
  __syncthreads();
#pragma unroll
  for (int i = 0; i < 32; i += 8)
    out[(size_t)(bx * 32 + y + i) * R + by * 32 + x] = f2bf(t[x][y + i]);
}

// ---------------------------------------------------------------------------
// Projection GEMM: C[m][n] = sum_k A[m][k] * BT[n][k], bf16 in, K=1024.
// FP8OUT=true writes e4m3(16*value) for the MX qk pass (8 MB output — byte
// stores fine at this size, verified rounds 0-2).
// ---------------------------------------------------------------------------
template <int NST, bool FP8OUT>
__global__ __launch_bounds__(256, 2)
void proj_gemm(const unsigned short* __restrict__ A,
               const unsigned short* __restrict__ BT,
               void* __restrict__ Cout) {
  __shared__ __align__(16) unsigned short As[2][128 * 64];
  __shared__ __align__(16) unsigned short Bs[2][128 * 64];
  const int tid = threadIdx.x;
  const int m0 = blockIdx.y * 128;
  const int n0 = blockIdx.x * 128;

  f32x4 acc[4][4];
#pragma unroll
  for (int a = 0; a < 4; a++)
#pragma unroll
    for (int b = 0; b < 4; b++) acc[a][b] = (f32x4){0.f, 0.f, 0.f, 0.f};

  mfma_core_db<DD, DD, DD>(A, BT, m0, n0, tid, As[0], As[1], Bs[0], Bs[1], acc);

  const int lane = tid & 63;
  const int w = tid >> 6;
  const int wr = (w >> 1) * 64, wc = (w & 1) * 64;
  const int l16 = lane & 15, lq = lane >> 4;
#pragma unroll
  for (int ti = 0; ti < 4; ti++)
#pragma unroll
    for (int r = 0; r < 4; r++) {
      const int row = m0 + wr + 16 * ti + lq * 4 + r;
#pragma unroll
      for (int tj = 0; tj < 4; tj++) {
        const int col = n0 + wc + 16 * tj + l16;
        if (FP8OUT) {
          ((unsigned char*)Cout)[(size_t)row * NST + col] =
              f2e4m3(acc[ti][tj][r] * 16.f);
        } else {
          ((unsigned short*)Cout)[(size_t)row * NST + col] = f2bf(acc[ti][tj][r]);
        }
      }
    }
}

// ---------------------------------------------------------------------------
// Pass 1: P = exp(xi @ xi^T) via MX-scaled fp8 MFMA.
// xif holds e4m3(16*xi); both MFMA scales = 2^-4 undo the pre-scaling.
// 128x128 tile, 4 waves, each 64x64 = 2x2 of mfma_scale_f32_32x32x64_f8f6f4.
//
// Round-5 diagnosis: ~1300 cy/K-step vs ~70 cy of MFMA — stage-latency-bound
// (vmcnt(0) drained cold each step).  Fix: 2-phase double-buffer; stage(t+1)
// issued before compute(t).  LDS 32 KB staging + 33 KB lsums = 65 KB @
// (256,2) -> 2 blocks/CU.
// Fused row sums: padded LDS lsums[128][65], one sync, 1 atomicAdd/row.
// P output stays bf16 — fp8 P measured 18x HBM write amplification (r3/r4).
// ---------------------------------------------------------------------------
__global__ __launch_bounds__(256, 2)
void qk_fp8(const unsigned char* __restrict__ xif,  // [8192][1024] e4m3(16*xi)
            unsigned short* __restrict__ P,         // [8192][8192] bf16 bits
            float* __restrict__ lsum) {             // [8192] fp32 (pre-zeroed)
  __shared__ __align__(16) unsigned char AsF[2][128 * 64];
  __shared__ __align__(16) unsigned char BsF[2][128 * 64];
  __shared__ float lsums[128][65];                  // padded, conflict-free
  const int tid = threadIdx.x;
  const int lane = tid & 63;
  const int w = tid >> 6;
  const int i0 = blockIdx.y * 128;
  const int j0 = blockIdx.x * 128;

  f32x16 acc[2][2];
#pragma unroll
  for (int a = 0; a < 2; a++)
#pragma unroll
    for (int b = 0; b < 2; b++)
#pragma unroll
      for (int r = 0; r < 16; r++) acc[a][b][r] = 0.f;

  const int srow = lane >> 2;  // 0..15: row within 16-row staging group
  const int slot = lane & 3;   // 16-B chunk slot within the row
  const int kb = lane >> 5;    // frag k-block (0/1)
  const int l31 = lane & 31;

  auto stage = [&](unsigned char* dA, unsigned char* dB, int kk) {
#pragma unroll
    for (int t = 0; t < 2; t++) {
      const int r = w * 32 + t * 16 + srow;
      const int c = slot ^ ((r >> 1) & 3);  // logical chunk for this slot
      const unsigned char* ga = &xif[(size_t)(i0 + r) * DD + kk + c * 16];
      const unsigned char* gb = &xif[(size_t)(j0 + r) * DD + kk + c * 16];
      __builtin_amdgcn_global_load_lds((gptr_t)(const void*)ga,
                                       (lptr_t)(void*)&dA[(w * 32 + t * 16) * 64],
                                       16, 0, 0);
      __builtin_amdgcn_global_load_lds((gptr_t)(const void*)gb,
                                       (lptr_t)(void*)&dB[(w * 32 + t * 16) * 64],
                                       16, 0, 0);
    }
  };

  stage(AsF[0], BsF[0], 0);
  asm volatile("s_waitcnt vmcnt(0)" ::: "memory");
  __syncthreads();

  unsigned char* curA = AsF[0];
  unsigned char* curB = BsF[0];
  unsigned char* nxtA = AsF[1];
  unsigned char* nxtB = BsF[1];
#pragma unroll 1
  for (int t = 0; t < DD / 64; t++) {
    if (t < DD / 64 - 1) stage(nxtA, nxtB, (t + 1) * 64);  // fly over compute

    i8v af[2], bf[2];
#pragma unroll
    for (int mi = 0; mi < 2; mi++) {
      const int ar = (w >> 1) * 64 + mi * 32 + l31;
      const int sw = (ar >> 1) & 3;
      const int4 q0 = *(const int4*)&curA[ar * 64 + ((2 * kb + 0) ^ sw) * 16];
      const int4 q1 = *(const int4*)&curA[ar * 64 + ((2 * kb + 1) ^ sw) * 16];
      af[mi] = make_i8v(q0, q1);
    }
#pragma unroll
    for (int nj = 0; nj < 2; nj++) {
      const int br = (w & 1) * 64 + nj * 32 + l31;
      const int sw = (br >> 1) & 3;
      const int4 q0 = *(const int4*)&curB[br * 64 + ((2 * kb + 0) ^ sw) * 16];
      const int4 q1 = *(const int4*)&curB[br * 64 + ((2 * kb + 1) ^ sw) * 16];
      bf[nj] = make_i8v(q0, q1);
    }
#pragma unroll
    for (int mi = 0; mi < 2; mi++)
#pragma unroll
      for (int nj = 0; nj < 2; nj++)
        acc[mi][nj] = __builtin_amdgcn_mfma_scale_f32_32x32x64_f8f6f4(
            af[mi], bf[nj], acc[mi][nj], 0 /*cbsz: fp8*/, 0 /*blgp: fp8*/,
            0, SCALE_1_16, 0, SCALE_1_16);

    asm volatile("s_waitcnt vmcnt(0)" ::: "memory");
    __syncthreads();
    unsigned char* tA = curA; curA = nxtA; nxtA = tA;
    unsigned char* tB = curB; curB = nxtB; nxtB = tB;
  }

  // Epilogue: p = exp(s) -> P (bf16) + LDS partial row sums.
  // 32x32 C layout: row = (reg&3) + 8*(reg>>2) + 4*(lane>>5), col = lane&31.
  const int mbase = (w >> 1) * 64;
  const int nbase = (w & 1) * 64;
  const int rowoff = 4 * (lane >> 5);
  const int cslot = (w & 1) * 32 + l31;  // column slot: wave n-half x lane
#pragma unroll
  for (int mi = 0; mi < 2; mi++)
#pragma unroll
    for (int r4 = 0; r4 < 4; r4++)
#pragma unroll
      for (int rr = 0; rr < 4; rr++) {
        const int reg = r4 * 4 + rr;
        const int rl = mbase + mi * 32 + rr + 8 * r4 + rowoff;
        const float p0 = __expf(acc[mi][0][reg]);
        const float p1 = __expf(acc[mi][1][reg]);
        const size_t base = (size_t)(i0 + rl) * NQ + j0 + nbase + l31;
        P[base]      = f2bf(p0);
        P[base + 32] = f2bf(p1);
        lsums[rl][cslot] = p0 + p1;  // each (rl,cslot) written exactly once
      }
  __syncthreads();
  if (tid < 128) {
    float s = 0.f;
#pragma unroll
    for (int c = 0; c < 64; c++) s += lsums[tid][c];
    atomicAdd(&lsum[i0 + tid], s);
  }
}

// ---------------------------------------------------------------------------
// Pass 2: out = (P @ supT^T) / lsum[row], K = 8192 (bf16).
// Round-0 geometry (128x128, 4 waves, 2 blocks/CU — proven 143us / 960 TF),
// now with the double-buffered core.  Grid x = i-tile (64), y = n-tile (8):
// FETCH was exactly P+supT read-once (144 MB) in rounds 0-2 — keep mapping.
// ---------------------------------------------------------------------------
__global__ __launch_bounds__(256, 2)
void pv(const unsigned short* __restrict__ P,
        const unsigned short* __restrict__ supT,
        const float* __restrict__ lsum,
        float* __restrict__ out) {
  __shared__ __align__(16) unsigned short As[2][128 * 64];
  __shared__ __align__(16) unsigned short Bs[2][128 * 64];
  const int tid = threadIdx.x;
  const int i0 = blockIdx.x * 128;
  const int n0 = blockIdx.y * 128;

  f32x4 acc[4][4];
#pragma unroll
  for (int a = 0; a < 4; a++)
#pragma unroll
    for (int b = 0; b < 4; b++) acc[a][b] = (f32x4){0.f, 0.f, 0.f, 0.f};

  mfma_core_db<NQ, NQ, NQ>(P, supT, i0, n0, tid, As[0], As[1], Bs[0], Bs[1],
                           acc);

  const int lane = tid & 63;
  const int w = tid >> 6;
  const int wr = (w >> 1) * 64, wc = (w & 1) * 64;
  const int l16 = lane & 15, lq = lane >> 4;
#pragma unroll
  for (int ti = 0; ti < 4; ti++) {
#pragma unroll
    for (int r = 0; r < 4; r++) {
      const int row = i0 + wr + 16 * ti + lq * 4 + r;
      const float linv = 1.f / lsum[row];
#pragma unroll
      for (int tj = 0; tj < 4; tj++) {
        const int col = n0 + wc + 16 * tj + l16;
        out[(size_t)row * DD + col] = acc[ti][tj][r] * linv;
      }
    }
  }
}

// ---------------------------------------------------------------------------
// Fallback fp32 path — only if ws_size is too small.
// ---------------------------------------------------------------------------
#define BM 64
#define BN 64
#define BK 16

__global__ __launch_bounds__(256, 4)
void gemm64(const float* __restrict__ A, const float* __restrict__ B,
            float* __restrict__ C, int M, int N, int K) {
  __shared__ __align__(16) float As[BK][BM + 4];
  __shared__ __align__(16) float Bs[BK][BN + 4];
  const int tid = threadIdx.x;
  const int tx = tid & 15;
  const int ty = tid >> 4;
  const int row0 = blockIdx.y * BM;
  const int col0 = blockIdx.x * BN;
  float acc[4][4] = {};
  for (int k0 = 0; k0 < K; k0 += BK) {
    {
      const int r = tid >> 2;
      const int c4 = (tid & 3) * 4;
      const float4 v = *(const float4*)&A[(size_t)(row0 + r) * K + k0 + c4];
      As[c4 + 0][r] = v.x; As[c4 + 1][r] = v.y;
      As[c4 + 2][r] = v.z; As[c4 + 3][r] = v.w;
    }
    {
      const int r = tid >> 4;
      const int c4 = (tid & 15) * 4;
      *(float4*)&Bs[r][c4] = *(const float4*)&B[(size_t)(k0 + r) * N + col0 + c4];
    }
    __syncthreads();
#pragma unroll
    for (int k = 0; k < BK; k++) {
      const float4 a = *(const float4*)&As[k][4 * ty];
      const float4 b = *(const float4*)&Bs[k][4 * tx];
      const float av[4] = {a.x, a.y, a.z, a.w};
      const float bv[4] = {b.x, b.y, b.z, b.w};
#pragma unroll
      for (int i = 0; i < 4; i++)
#pragma unroll
        for (int j = 0; j < 4; j++)
          acc[i][j] += av[i] * bv[j];
    }
    __syncthreads();
  }
#pragma unroll
  for (int i = 0; i < 4; i++) {
    float4 o = {acc[i][0], acc[i][1], acc[i][2], acc[i][3]};
    *(float4*)&C[(size_t)(row0 + 4 * ty + i) * N + col0 + 4 * tx] = o;
  }
}

#define IT 32
#define JT 128
#define KC 32
#define CC 128
#define NCH (DD / CC)

__global__ __launch_bounds__(256, 1)
void fused_attn(const float* __restrict__ xi, const float* __restrict__ sup,
                float* __restrict__ out) {
  __shared__ __align__(16) float XiI[KC][IT + 4];
  __shared__ __align__(16) float XiJ[KC][JT + 4];
  __shared__ __align__(16) float Ps[JT][IT + 4];
  __shared__ __align__(16) float Vs[JT][CC + 4];
  __shared__ float lsum[IT];
  const int tid = threadIdx.x;
  const int i0 = blockIdx.x * IT;
  const int ry = tid >> 5;
  const int cx = tid & 31;
  if (tid < IT) lsum[tid] = 0.f;
  float oacc[NCH][4][4];
#pragma unroll
  for (int ch = 0; ch < NCH; ch++)
#pragma unroll
    for (int i = 0; i < 4; i++)
#pragma unroll
      for (int j = 0; j < 4; j++) oacc[ch][i][j] = 0.f;
  for (int j0 = 0; j0 < NQ; j0 += JT) {
    float sacc[4][4] = {};
    for (int kc = 0; kc < DD; kc += KC) {
      __syncthreads();
      {
        const int r = tid >> 3;
        const int k4 = (tid & 7) * 4;
        const float4 v = *(const float4*)&xi[(size_t)(i0 + r) * DD + kc + k4];
        XiI[k4 + 0][r] = v.x; XiI[k4 + 1][r] = v.y;
        XiI[k4 + 2][r] = v.z; XiI[k4 + 3][r] = v.w;
      }
#pragma unroll
      for (int i = 0; i < 4; i++) {
        const int idx = tid + i * 256;
        const int r = idx >> 3;
        const int k4 = (idx & 7) * 4;
        const float4 v = *(const float4*)&xi[(size_t)(j0 + r) * DD + kc + k4];
        XiJ[k4 + 0][r] = v.x; XiJ[k4 + 1][r] = v.y;
        XiJ[k4 + 2][r] = v.z; XiJ[k4 + 3][r] = v.w;
      }
      __syncthreads();
#pragma unroll
      for (int k = 0; k < KC; k++) {
        const float4 a = *(const float4*)&XiI[k][4 * ry];
        const float4 b = *(const float4*)&XiJ[k][4 * cx];
        const float av[4] = {a.x, a.y, a.z, a.w};
        const float bv[4] = {b.x, b.y, b.z, b.w};
#pragma unroll
        for (int i = 0; i < 4; i++)
#pragma unroll
          for (int j = 0; j < 4; j++)
            sacc[i][j] += av[i] * bv[j];
      }
    }
    __syncthreads();
    float rsv[4] = {0.f, 0.f, 0.f, 0.f};
#pragma unroll
    for (int i = 0; i < 4; i++)
#pragma unroll
      for (int j = 0; j < 4; j++) {
        const float p = __expf(sacc[i][j]);
        Ps[4 * cx + j][4 * ry + i] = p;
        rsv[i] += p;
      }
#pragma unroll
    for (int m = 16; m >= 1; m >>= 1)
#pragma unroll
      for (int i = 0; i < 4; i++) rsv[i] += __shfl_xor(rsv[i], m);
    if (cx == 0) {
#pragma unroll
      for (int i = 0; i < 4; i++) lsum[4 * ry + i] += rsv[i];
    }
    for (int ch = 0; ch < NCH; ch++) {
      __syncthreads();
#pragma unroll
      for (int i = 0; i < 16; i++) {
        const int idx = tid + i * 256;
        const int r = idx >> 5;
        const int c4 = (idx & 31) * 4;
        *(float4*)&Vs[r][c4] =
            *(const float4*)&sup[(size_t)(j0 + r) * DD + ch * CC + c4];
      }
      __syncthreads();
#pragma unroll 4
      for (int jp = 0; jp < JT; jp++) {
        const float4 p = *(const float4*)&Ps[jp][4 * ry];
        const float4 v = *(const float4*)&Vs[jp][4 * cx];
        const float pvv[4] = {p.x, p.y, p.z, p.w};
        const float vv[4] = {v.x, v.y, v.z, v.w};
#pragma unroll
        for (int i = 0; i < 4; i++)
#pragma unroll
          for (int j = 0; j < 4; j++)
            oacc[ch][i][j] += pvv[i] * vv[j];
      }
    }
  }
  __syncthreads();
  float linv[4];
#pragma unroll
  for (int i = 0; i < 4; i++) linv[i] = 1.f / lsum[4 * ry + i];
#pragma unroll
  for (int ch = 0; ch < NCH; ch++)
#pragma unroll
    for (int i = 0; i < 4; i++) {
      float4 o = {oacc[ch][i][0] * linv[i], oacc[ch][i][1] * linv[i],
                  oacc[ch][i][2] * linv[i], oacc[ch][i][3] * linv[i]};
      *(float4*)&out[(size_t)(i0 + 4 * ry + i) * DD + ch * CC + 4 * cx] = o;
    }
}

// ---------------------------------------------------------------------------
// Launch. ws layout (MFMA path, NEED = 152 MB + 32 KB):
//   P    : [0, 128MB)    bf16 [8192][8192]
//   xif  : [128,136MB)   e4m3 [8192][1024] (= fp8(16*xi))
//   supT : [136,152MB)   bf16 [1024][8192]
//   lsum : [152MB,+32KB) fp32 [8192]  (zeroed, filled by qk_fp8 atomics)
//   transients (consumed before P is written, alias the P region):
//     xb [0,16MB) bf16 [8192][1024];  tiT [16,18MB);  wT [18,20MB)
// NOTE: reference uses transferi for BOTH projections; transferj unused.
// ---------------------------------------------------------------------------
extern "C" void kernel_launch(void* const* d_in, const int* in_sizes, int n_in,
                              void* d_out, int out_size, void* d_ws, size_t ws_size,
                              hipStream_t stream) {
  const float* x  = (const float*)d_in[0];
  const float* wt = (const float*)d_in[1];
  const float* ti = (const float*)d_in[2];
  float* out = (float*)d_out;

  char* ws = (char*)d_ws;
  const size_t MB = 1024 * 1024;
  const size_t NEED = 152 * MB + NQ * sizeof(float);

  if (ws_size >= NEED) {
    unsigned short* P    = (unsigned short*)ws;
    unsigned char*  xif  = (unsigned char*)(ws + 128 * MB);
    unsigned short* supT = (unsigned short*)(ws + 136 * MB);
    float* lsum          = (float*)(ws + 152 * MB);
    unsigned short* xb   = (unsigned short*)ws;             // transient in P
    unsigned short* tiT  = (unsigned short*)(ws + 16 * MB); // transient in P
    unsigned short* wT   = (unsigned short*)(ws + 18 * MB); // transient in P

    const int n4 = NQ * DD / 4;
    zero_f32<<<NQ / 256, 256, 0, stream>>>(lsum, NQ);
    f32_to_bf16<<<(n4 + 255) / 256, 256, 0, stream>>>(x, xb, n4);
    transpose_cvt<<<dim3(32, 32), 256, 0, stream>>>(ti, tiT, DD, DD);
    transpose_cvt<<<dim3(32, 32), 256, 0, stream>>>(wt, wT, DD, DD);

    // xif[m][n] = e4m3(16 * sum_k xb[m][k]*ti[k][n])
    proj_gemm<DD, true><<<dim3(DD / 128, NQ / 128), 256, 0, stream>>>(xb, tiT, xif);
    // supT[n][m] = bf16(sum_k W[k][n]*x[m][k])
    proj_gemm<NQ, false><<<dim3(NQ / 128, DD / 128), 256, 0, stream>>>(wT, xb, supT);

    qk_fp8<<<dim3(NQ / 128, NQ / 128), 256, 0, stream>>>(xif, P, lsum);
    pv<<<dim3(NQ / 128, DD / 128), 256, 0, stream>>>(P, supT, lsum, out);
  } else {
    float* xi32  = (float*)ws;
    float* sup32 = (float*)(ws + 32 * MB);
    dim3 ggrid(DD / BN, NQ / BM);
    gemm64<<<ggrid, 256, 0, stream>>>(x, ti, xi32, NQ, DD, DD);
    gemm64<<<ggrid, 256, 0, stream>>>(x, wt, sup32, NQ, DD, DD);
    fused_attn<<<NQ / IT, 256, 0, stream>>>(xi32, sup32, out);
  }
}

// Round 7
// 353.313 us; speedup vs baseline: 2.1331x; 1.0483x over previous
//
#include <hip/hip_runtime.h>
#include <hip/hip_bf16.h>
#include <cstddef>

// Problem constants (match reference).
#define NQ 8192
#define DD 1024

typedef __attribute__((ext_vector_type(8))) short s8v;     // 8 bf16 (4 VGPR)
typedef __attribute__((ext_vector_type(8))) int i8v;       // 32 fp8 bytes (8 VGPR)
typedef __attribute__((ext_vector_type(4))) float f32x4;   // 16x16 C/D frag
typedef __attribute__((ext_vector_type(16))) float f32x16; // 32x32 C/D frag

typedef const __attribute__((address_space(1))) unsigned int* gptr_t;
typedef __attribute__((address_space(3))) unsigned int* lptr_t;

#define SCALE_1_16 0x7B7B7B7Bu  // E8M0 123 = 2^-4 in every byte

__device__ inline unsigned short f2bf(float f) {
  union { float f; unsigned u; } v; v.f = f;
  unsigned r = (v.u + 0x7FFFu + ((v.u >> 16) & 1u)) >> 16;  // RNE
  return (unsigned short)r;
}
__device__ inline float bits2f(unsigned u) {
  union { unsigned u; float f; } v; v.u = u;
  return v.f;
}

// f32 -> OCP e4m3 bits, RNE, clamp to +-448.
__device__ inline unsigned char f2e4m3(float x) {
  union { float f; unsigned u; } v; v.f = x;
  const unsigned s = (v.u >> 31) << 7;
  unsigned au = v.u & 0x7FFFFFFFu;
  if (au > 0x43E00000u) au = 0x43E00000u;  // clamp |x| to 448.0
  if (au >= 0x3C800000u) {                 // |x| >= 2^-6: e4m3 normal
    const unsigned rounded = au + 0x7FFFFu + ((au >> 20) & 1u);  // RNE @ 3 mant
    const unsigned e8 = ((rounded >> 23) & 0xFF) - 120u;         // -127+7
    const unsigned m8 = (rounded >> 20) & 7u;
    return (unsigned char)(s | (e8 << 3) | m8);
  } else {                                 // subnormal
    union { unsigned u; float f; } a; a.u = au;
    const unsigned q = (unsigned)rintf(a.f * 512.0f);  // 0..8
    return (unsigned char)(s | q);
  }
}

// Register-only combine of two 16-B LDS loads into one fp8 MFMA operand.
__device__ inline i8v make_i8v(int4 a, int4 b) {
  i8v v;
  v[0] = a.x; v[1] = a.y; v[2] = a.z; v[3] = a.w;
  v[4] = b.x; v[5] = b.y; v[6] = b.z; v[7] = b.w;
  return v;
}

// ---------------------------------------------------------------------------
// Double-buffered m97-style bf16 MFMA loop: C(128x128) += A(128xK) @ B(128xK)^T.
// stage(t+1) ISSUED before compute(t); one vmcnt(0)+barrier per K-step.
// Proven round-6: pv 143 -> 128.6 us, MfmaUtil 48%.
// XOR-swizzled 16-B chunks, 0 bank conflicts (verified round-0).
// ---------------------------------------------------------------------------
template <int KDIM, int ASTR, int BSTR>
__device__ inline void mfma_core_db(const unsigned short* __restrict__ A,
                                    const unsigned short* __restrict__ B,
                                    int i0, int j0, int tid,
                                    unsigned short* __restrict__ As0,
                                    unsigned short* __restrict__ As1,
                                    unsigned short* __restrict__ Bs0,
                                    unsigned short* __restrict__ Bs1,
                                    f32x4 (&acc)[4][4]) {
  const int lane = tid & 63;
  const int w = tid >> 6;
  const int wr = (w >> 1) * 64;
  const int wc = (w & 1) * 64;
  const int l16 = lane & 15;
  const int lq = lane >> 4;
  const int srow = lane >> 3;                          // 0..7
  const int scol = (((lane & 7) ^ (srow & 7)) * 8);    // swizzled 16-B chunk

  auto stage = [&](unsigned short* dA, unsigned short* dB, int kk) {
#pragma unroll
    for (int t = 0; t < 4; t++) {
      const int r0 = w * 32 + t * 8;
      const unsigned short* g = &A[(size_t)(i0 + r0 + srow) * ASTR + kk + scol];
      __builtin_amdgcn_global_load_lds((gptr_t)(const void*)g,
                                       (lptr_t)(void*)&dA[r0 * 64], 16, 0, 0);
    }
#pragma unroll
    for (int t = 0; t < 4; t++) {
      const int r0 = w * 32 + t * 8;
      const unsigned short* g = &B[(size_t)(j0 + r0 + srow) * BSTR + kk + scol];
      __builtin_amdgcn_global_load_lds((gptr_t)(const void*)g,
                                       (lptr_t)(void*)&dB[r0 * 64], 16, 0, 0);
    }
  };

  stage(As0, Bs0, 0);
  asm volatile("s_waitcnt vmcnt(0)" ::: "memory");
  __syncthreads();

  const int h = l16 & 7;
  unsigned short* curA = As0;
  unsigned short* curB = Bs0;
  unsigned short* nxtA = As1;
  unsigned short* nxtB = Bs1;
#pragma unroll 1
  for (int t = 0; t < KDIM / 64; t++) {
    if (t < KDIM / 64 - 1) stage(nxtA, nxtB, (t + 1) * 64);  // fly over compute
    s8v af[4][2], bf[4][2];
#pragma unroll
    for (int q = 0; q < 4; q++)
#pragma unroll
      for (int s = 0; s < 2; s++) {
        const int ch = ((s * 4 + lq) ^ h) * 8;  // swizzled chunk offset
        af[q][s] = *(const s8v*)&curA[(wr + 16 * q + l16) * 64 + ch];
        bf[q][s] = *(const s8v*)&curB[(wc + 16 * q + l16) * 64 + ch];
      }
#pragma unroll
    for (int s = 0; s < 2; s++)
#pragma unroll
      for (int a = 0; a < 4; a++)
#pragma unroll
        for (int b = 0; b < 4; b++)
          acc[a][b] = __builtin_amdgcn_mfma_f32_16x16x32_bf16(
              af[a][s], bf[b][s], acc[a][b], 0, 0, 0);
    asm volatile("s_waitcnt vmcnt(0)" ::: "memory");  // next buffer landed
    __syncthreads();
    unsigned short* tA = curA; curA = nxtA; nxtA = tA;
    unsigned short* tB = curB; curB = nxtB; nxtB = tB;
  }
}

// ---------------------------------------------------------------------------
// fp32 -> bf16 elementwise.
// ---------------------------------------------------------------------------
__global__ void f32_to_bf16(const float* __restrict__ in,
                            unsigned short* __restrict__ out, int n4) {
  int i = (blockIdx.x * blockDim.x + threadIdx.x);
  if (i < n4) {
    const float4 v = *(const float4*)&in[i * 4];
    ushort4 o;
    o.x = f2bf(v.x); o.y = f2bf(v.y); o.z = f2bf(v.z); o.w = f2bf(v.w);
    *(ushort4*)&out[i * 4] = o;
  }
}

__global__ void zero_f32(float* __restrict__ p, int n) {
  const int i = blockIdx.x * blockDim.x + threadIdx.x;
  if (i < n) p[i] = 0.f;
}

// ---------------------------------------------------------------------------
// fp32 [R][C] -> bf16 [C][R] transpose+convert (32x32 LDS tiles).
// ---------------------------------------------------------------------------
__global__ void transpose_cvt(const float* __restrict__ in,
                              unsigned short* __restrict__ out, int R, int C) {
  __shared__ float t[32][33];
  const int bx = blockIdx.x;
  const int by = blockIdx.y;
  const int x = threadIdx.x & 31;
  const int y = threadIdx.x >> 5;
#pragma unroll
  for (int i = 0; i < 32; i += 8)
    t[y + i][x] = in[(size_t)(by * 32 + y + i) * C + bx * 32 + x];
  __syncthreads();
#pragma unroll
  for (int i = 0; i < 32; i += 8)
    out[(size_t)(bx * 32 + y + i) * R + by * 32 + x] = f2bf(t[x][y + i]);
}

// ---------------------------------------------------------------------------
// Projection GEMM: C[m][n] = sum_k A[m][k] * BT[n][k], bf16 in, K=1024.
// FP8OUT=true writes e4m3(16*value) for the MX qk pass (8 MB output — byte
// stores fine at this size, verified rounds 0-2).
// ---------------------------------------------------------------------------
template <int NST, bool FP8OUT>
__global__ __launch_bounds__(256, 2)
void proj_gemm(const unsigned short* __restrict__ A,
               const unsigned short* __restrict__ BT,
               void* __restrict__ Cout) {
  __shared__ __align__(16) unsigned short As[2][128 * 64];
  __shared__ __align__(16) unsigned short Bs[2][128 * 64];
  const int tid = threadIdx.x;
  const int m0 = blockIdx.y * 128;
  const int n0 = blockIdx.x * 128;

  f32x4 acc[4][4];
#pragma unroll
  for (int a = 0; a < 4; a++)
#pragma unroll
    for (int b = 0; b < 4; b++) acc[a][b] = (f32x4){0.f, 0.f, 0.f, 0.f};

  mfma_core_db<DD, DD, DD>(A, BT, m0, n0, tid, As[0], As[1], Bs[0], Bs[1], acc);

  const int lane = tid & 63;
  const int w = tid >> 6;
  const int wr = (w >> 1) * 64, wc = (w & 1) * 64;
  const int l16 = lane & 15, lq = lane >> 4;
#pragma unroll
  for (int ti = 0; ti < 4; ti++)
#pragma unroll
    for (int r = 0; r < 4; r++) {
      const int row = m0 + wr + 16 * ti + lq * 4 + r;
#pragma unroll
      for (int tj = 0; tj < 4; tj++) {
        const int col = n0 + wc + 16 * tj + l16;
        if (FP8OUT) {
          ((unsigned char*)Cout)[(size_t)row * NST + col] =
              f2e4m3(acc[ti][tj][r] * 16.f);
        } else {
          ((unsigned short*)Cout)[(size_t)row * NST + col] = f2bf(acc[ti][tj][r]);
        }
      }
    }
}

// ---------------------------------------------------------------------------
// Pass 1: P = exp(xi @ xi^T) via MX-scaled fp8 MFMA.
// xif holds e4m3(16*xi); both MFMA scales = 2^-4 undo the pre-scaling.
// 128x128 tile, 4 waves, each 64x64 = 2x2 of mfma_scale_f32_32x32x64_f8f6f4.
//
// Round-7: LDS OVERLAY — staging dbuf (32 KB), lsums[128][65] (33.3 KB) and
// the bf16 out-tile (32 KB) time-share one 33.3 KB region (staging dead when
// epilogue starts; phases barrier-separated).  LDS 65 -> 33.3 KB restores
// 3 blocks/CU WITH the double buffer.  P written via LDS tile then 16-B
// dwordx4 (256-B segments/row): 2k wide stores replace 16k scattered 2-B
// stores (round-6 diagnosis: epilogue-bound).
// ---------------------------------------------------------------------------
__global__ __launch_bounds__(256, 3)
void qk_fp8(const unsigned char* __restrict__ xif,  // [8192][1024] e4m3(16*xi)
            unsigned short* __restrict__ P,         // [8192][8192] bf16 bits
            float* __restrict__ lsum) {             // [8192] fp32 (pre-zeroed)
  __shared__ __align__(16) unsigned char smem[128 * 65 * 4];  // 33.3 KB overlay
  unsigned char* AsF0 = smem;                 // 8 KB
  unsigned char* BsF0 = smem + 8192;          // 8 KB
  unsigned char* AsF1 = smem + 16384;         // 8 KB
  unsigned char* BsF1 = smem + 24576;         // 8 KB
  const int tid = threadIdx.x;
  const int lane = tid & 63;
  const int w = tid >> 6;
  const int i0 = blockIdx.y * 128;
  const int j0 = blockIdx.x * 128;

  f32x16 acc[2][2];
#pragma unroll
  for (int a = 0; a < 2; a++)
#pragma unroll
    for (int b = 0; b < 2; b++)
#pragma unroll
      for (int r = 0; r < 16; r++) acc[a][b][r] = 0.f;

  const int srow = lane >> 2;  // 0..15: row within 16-row staging group
  const int slot = lane & 3;   // 16-B chunk slot within the row
  const int kb = lane >> 5;    // frag k-block (0/1)
  const int l31 = lane & 31;

  auto stage = [&](unsigned char* dA, unsigned char* dB, int kk) {
#pragma unroll
    for (int t = 0; t < 2; t++) {
      const int r = w * 32 + t * 16 + srow;
      const int c = slot ^ ((r >> 1) & 3);  // logical chunk for this slot
      const unsigned char* ga = &xif[(size_t)(i0 + r) * DD + kk + c * 16];
      const unsigned char* gb = &xif[(size_t)(j0 + r) * DD + kk + c * 16];
      __builtin_amdgcn_global_load_lds((gptr_t)(const void*)ga,
                                       (lptr_t)(void*)&dA[(w * 32 + t * 16) * 64],
                                       16, 0, 0);
      __builtin_amdgcn_global_load_lds((gptr_t)(const void*)gb,
                                       (lptr_t)(void*)&dB[(w * 32 + t * 16) * 64],
                                       16, 0, 0);
    }
  };

  stage(AsF0, BsF0, 0);
  asm volatile("s_waitcnt vmcnt(0)" ::: "memory");
  __syncthreads();

  unsigned char* curA = AsF0;
  unsigned char* curB = BsF0;
  unsigned char* nxtA = AsF1;
  unsigned char* nxtB = BsF1;
#pragma unroll 1
  for (int t = 0; t < DD / 64; t++) {
    if (t < DD / 64 - 1) stage(nxtA, nxtB, (t + 1) * 64);  // fly over compute

    i8v af[2], bf[2];
#pragma unroll
    for (int mi = 0; mi < 2; mi++) {
      const int ar = (w >> 1) * 64 + mi * 32 + l31;
      const int sw = (ar >> 1) & 3;
      const int4 q0 = *(const int4*)&curA[ar * 64 + ((2 * kb + 0) ^ sw) * 16];
      const int4 q1 = *(const int4*)&curA[ar * 64 + ((2 * kb + 1) ^ sw) * 16];
      af[mi] = make_i8v(q0, q1);
    }
#pragma unroll
    for (int nj = 0; nj < 2; nj++) {
      const int br = (w & 1) * 64 + nj * 32 + l31;
      const int sw = (br >> 1) & 3;
      const int4 q0 = *(const int4*)&curB[br * 64 + ((2 * kb + 0) ^ sw) * 16];
      const int4 q1 = *(const int4*)&curB[br * 64 + ((2 * kb + 1) ^ sw) * 16];
      bf[nj] = make_i8v(q0, q1);
    }
#pragma unroll
    for (int mi = 0; mi < 2; mi++)
#pragma unroll
      for (int nj = 0; nj < 2; nj++)
        acc[mi][nj] = __builtin_amdgcn_mfma_scale_f32_32x32x64_f8f6f4(
            af[mi], bf[nj], acc[mi][nj], 0 /*cbsz: fp8*/, 0 /*blgp: fp8*/,
            0, SCALE_1_16, 0, SCALE_1_16);

    asm volatile("s_waitcnt vmcnt(0)" ::: "memory");
    __syncthreads();
    unsigned char* tA = curA; curA = nxtA; nxtA = tA;
    unsigned char* tB = curB; curB = nxtB; nxtB = tB;
  }
  // Loop ends with a full barrier: smem staging region is dead from here.

  // exp into registers (acc dies here; compiler reuses).
  // 32x32 C layout: row = (reg&3) + 8*(reg>>2) + 4*(lane>>5), col = lane&31.
  float ex0[2][16], ex1[2][16];
#pragma unroll
  for (int mi = 0; mi < 2; mi++)
#pragma unroll
    for (int reg = 0; reg < 16; reg++) {
      ex0[mi][reg] = __expf(acc[mi][0][reg]);
      ex1[mi][reg] = __expf(acc[mi][1][reg]);
    }

  const int mbase = (w >> 1) * 64;
  const int nbase = (w & 1) * 64;
  const int rowoff = 4 * (lane >> 5);
  const int cslot = (w & 1) * 32 + l31;  // column slot: wave n-half x lane

  // Phase A: lsums partials in the overlay, reduce, one atomicAdd per row.
  float (*lsums)[65] = (float (*)[65])smem;  // 33.3 KB, padded stride
#pragma unroll
  for (int mi = 0; mi < 2; mi++)
#pragma unroll
    for (int r4 = 0; r4 < 4; r4++)
#pragma unroll
      for (int rr = 0; rr < 4; rr++) {
        const int reg = r4 * 4 + rr;
        const int rl = mbase + mi * 32 + rr + 8 * r4 + rowoff;
        lsums[rl][cslot] = ex0[mi][reg] + ex1[mi][reg];
      }
  __syncthreads();
  if (tid < 128) {
    float s = 0.f;
#pragma unroll
    for (int c = 0; c < 64; c++) s += lsums[tid][c];
    atomicAdd(&lsum[i0 + tid], s);
  }
  __syncthreads();  // lsums reads drained before tile overwrite

  // Phase B: bf16 tile in the overlay, then coalesced 256-B row stores.
  unsigned short* tile = (unsigned short*)smem;  // [128][128]
#pragma unroll
  for (int mi = 0; mi < 2; mi++)
#pragma unroll
    for (int r4 = 0; r4 < 4; r4++)
#pragma unroll
      for (int rr = 0; rr < 4; rr++) {
        const int reg = r4 * 4 + rr;
        const int rl = mbase + mi * 32 + rr + 8 * r4 + rowoff;
        tile[rl * 128 + nbase + l31]      = f2bf(ex0[mi][reg]);
        tile[rl * 128 + nbase + l31 + 32] = f2bf(ex1[mi][reg]);
      }
  __syncthreads();
  {
    const int rr2 = tid >> 4;       // 0..15: row within 16-row group
    const int ch = (tid & 15) * 8;  // 8 shorts = 16 B; 16 lanes = 256 B/row
#pragma unroll
    for (int q = 0; q < 8; q++) {
      const int row = rr2 + q * 16;
      const int4 v = *(const int4*)&tile[row * 128 + ch];
      *(int4*)&P[(size_t)(i0 + row) * NQ + j0 + ch] = v;
    }
  }
}

// ---------------------------------------------------------------------------
// Pass 2: out = (P @ supT^T) / lsum[row], K = 8192 (bf16).
// Round-6 proven: 128.6 us, MfmaUtil 48%, ~LDS-BW floor for this geometry.
// ---------------------------------------------------------------------------
__global__ __launch_bounds__(256, 2)
void pv(const unsigned short* __restrict__ P,
        const unsigned short* __restrict__ supT,
        const float* __restrict__ lsum,
        float* __restrict__ out) {
  __shared__ __align__(16) unsigned short As[2][128 * 64];
  __shared__ __align__(16) unsigned short Bs[2][128 * 64];
  const int tid = threadIdx.x;
  const int i0 = blockIdx.x * 128;
  const int n0 = blockIdx.y * 128;

  f32x4 acc[4][4];
#pragma unroll
  for (int a = 0; a < 4; a++)
#pragma unroll
    for (int b = 0; b < 4; b++) acc[a][b] = (f32x4){0.f, 0.f, 0.f, 0.f};

  mfma_core_db<NQ, NQ, NQ>(P, supT, i0, n0, tid, As[0], As[1], Bs[0], Bs[1],
                           acc);

  const int lane = tid & 63;
  const int w = tid >> 6;
  const int wr = (w >> 1) * 64, wc = (w & 1) * 64;
  const int l16 = lane & 15, lq = lane >> 4;
#pragma unroll
  for (int ti = 0; ti < 4; ti++) {
#pragma unroll
    for (int r = 0; r < 4; r++) {
      const int row = i0 + wr + 16 * ti + lq * 4 + r;
      const float linv = 1.f / lsum[row];
#pragma unroll
      for (int tj = 0; tj < 4; tj++) {
        const int col = n0 + wc + 16 * tj + l16;
        out[(size_t)row * DD + col] = acc[ti][tj][r] * linv;
      }
    }
  }
}

// ---------------------------------------------------------------------------
// Fallback fp32 path — only if ws_size is too small.
// ---------------------------------------------------------------------------
#define BM 64
#define BN 64
#define BK 16

__global__ __launch_bounds__(256, 4)
void gemm64(const float* __restrict__ A, const float* __restrict__ B,
            float* __restrict__ C, int M, int N, int K) {
  __shared__ __align__(16) float As[BK][BM + 4];
  __shared__ __align__(16) float Bs[BK][BN + 4];
  const int tid = threadIdx.x;
  const int tx = tid & 15;
  const int ty = tid >> 4;
  const int row0 = blockIdx.y * BM;
  const int col0 = blockIdx.x * BN;
  float acc[4][4] = {};
  for (int k0 = 0; k0 < K; k0 += BK) {
    {
      const int r = tid >> 2;
      const int c4 = (tid & 3) * 4;
      const float4 v = *(const float4*)&A[(size_t)(row0 + r) * K + k0 + c4];
      As[c4 + 0][r] = v.x; As[c4 + 1][r] = v.y;
      As[c4 + 2][r] = v.z; As[c4 + 3][r] = v.w;
    }
    {
      const int r = tid >> 4;
      const int c4 = (tid & 15) * 4;
      *(float4*)&Bs[r][c4] = *(const float4*)&B[(size_t)(k0 + r) * N + col0 + c4];
    }
    __syncthreads();
#pragma unroll
    for (int k = 0; k < BK; k++) {
      const float4 a = *(const float4*)&As[k][4 * ty];
      const float4 b = *(const float4*)&Bs[k][4 * tx];
      const float av[4] = {a.x, a.y, a.z, a.w};
      const float bv[4] = {b.x, b.y, b.z, b.w};
#pragma unroll
      for (int i = 0; i < 4; i++)
#pragma unroll
        for (int j = 0; j < 4; j++)
          acc[i][j] += av[i] * bv[j];
    }
    __syncthreads();
  }
#pragma unroll
  for (int i = 0; i < 4; i++) {
    float4 o = {acc[i][0], acc[i][1], acc[i][2], acc[i][3]};
    *(float4*)&C[(size_t)(row0 + 4 * ty + i) * N + col0 + 4 * tx] = o;
  }
}

#define IT 32
#define JT 128
#define KC 32
#define CC 128
#define NCH (DD / CC)

__global__ __launch_bounds__(256, 1)
void fused_attn(const float* __restrict__ xi, const float* __restrict__ sup,
                float* __restrict__ out) {
  __shared__ __align__(16) float XiI[KC][IT + 4];
  __shared__ __align__(16) float XiJ[KC][JT + 4];
  __shared__ __align__(16) float Ps[JT][IT + 4];
  __shared__ __align__(16) float Vs[JT][CC + 4];
  __shared__ float lsum[IT];
  const int tid = threadIdx.x;
  const int i0 = blockIdx.x * IT;
  const int ry = tid >> 5;
  const int cx = tid & 31;
  if (tid < IT) lsum[tid] = 0.f;
  float oacc[NCH][4][4];
#pragma unroll
  for (int ch = 0; ch < NCH; ch++)
#pragma unroll
    for (int i = 0; i < 4; i++)
#pragma unroll
      for (int j = 0; j < 4; j++) oacc[ch][i][j] = 0.f;
  for (int j0 = 0; j0 < NQ; j0 += JT) {
    float sacc[4][4] = {};
    for (int kc = 0; kc < DD; kc += KC) {
      __syncthreads();
      {
        const int r = tid >> 3;
        const int k4 = (tid & 7) * 4;
        const float4 v = *(const float4*)&xi[(size_t)(i0 + r) * DD + kc + k4];
        XiI[k4 + 0][r] = v.x; XiI[k4 + 1][r] = v.y;
        XiI[k4 + 2][r] = v.z; XiI[k4 + 3][r] = v.w;
      }
#pragma unroll
      for (int i = 0; i < 4; i++) {
        const int idx = tid + i * 256;
        const int r = idx >> 3;
        const int k4 = (idx & 7) * 4;
        const float4 v = *(const float4*)&xi[(size_t)(j0 + r) * DD + kc + k4];
        XiJ[k4 + 0][r] = v.x; XiJ[k4 + 1][r] = v.y;
        XiJ[k4 + 2][r] = v.z; XiJ[k4 + 3][r] = v.w;
      }
      __syncthreads();
#pragma unroll
      for (int k = 0; k < KC; k++) {
        const float4 a = *(const float4*)&XiI[k][4 * ry];
        const float4 b = *(const float4*)&XiJ[k][4 * cx];
        const float av[4] = {a.x, a.y, a.z, a.w};
        const float bv[4] = {b.x, b.y, b.z, b.w};
#pragma unroll
        for (int i = 0; i < 4; i++)
#pragma unroll
          for (int j = 0; j < 4; j++)
            sacc[i][j] += av[i] * bv[j];
      }
    }
    __syncthreads();
    float rsv[4] = {0.f, 0.f, 0.f, 0.f};
#pragma unroll
    for (int i = 0; i < 4; i++)
#pragma unroll
      for (int j = 0; j < 4; j++) {
        const float p = __expf(sacc[i][j]);
        Ps[4 * cx + j][4 * ry + i] = p;
        rsv[i] += p;
      }
#pragma unroll
    for (int m = 16; m >= 1; m >>= 1)
#pragma unroll
      for (int i = 0; i < 4; i++) rsv[i] += __shfl_xor(rsv[i], m);
    if (cx == 0) {
#pragma unroll
      for (int i = 0; i < 4; i++) lsum[4 * ry + i] += rsv[i];
    }
    for (int ch = 0; ch < NCH; ch++) {
      __syncthreads();
#pragma unroll
      for (int i = 0; i < 16; i++) {
        const int idx = tid + i * 256;
        const int r = idx >> 5;
        const int c4 = (idx & 31) * 4;
        *(float4*)&Vs[r][c4] =
            *(const float4*)&sup[(size_t)(j0 + r) * DD + ch * CC + c4];
      }
      __syncthreads();
#pragma unroll 4
      for (int jp = 0; jp < JT; jp++) {
        const float4 p = *(const float4*)&Ps[jp][4 * ry];
        const float4 v = *(const float4*)&Vs[jp][4 * cx];
        const float pvv[4] = {p.x, p.y, p.z, p.w};
        const float vv[4] = {v.x, v.y, v.z, v.w};
#pragma unroll
        for (int i = 0; i < 4; i++)
#pragma unroll
          for (int j = 0; j < 4; j++)
            oacc[ch][i][j] += pvv[i] * vv[j];
      }
    }
  }
  __syncthreads();
  float linv[4];
#pragma unroll
  for (int i = 0; i < 4; i++) linv[i] = 1.f / lsum[4 * ry + i];
#pragma unroll
  for (int ch = 0; ch < NCH; ch++)
#pragma unroll
    for (int i = 0; i < 4; i++) {
      float4 o = {oacc[ch][i][0] * linv[i], oacc[ch][i][1] * linv[i],
                  oacc[ch][i][2] * linv[i], oacc[ch][i][3] * linv[i]};
      *(float4*)&out[(size_t)(i0 + 4 * ry + i) * DD + ch * CC + 4 * cx] = o;
    }
}

// ---------------------------------------------------------------------------
// Launch. ws layout (MFMA path, NEED = 152 MB + 32 KB):
//   P    : [0, 128MB)    bf16 [8192][8192]
//   xif  : [128,136MB)   e4m3 [8192][1024] (= fp8(16*xi))
//   supT : [136,152MB)   bf16 [1024][8192]
//   lsum : [152MB,+32KB) fp32 [8192]  (zeroed, filled by qk_fp8 atomics)
//   transients (consumed before P is written, alias the P region):
//     xb [0,16MB) bf16 [8192][1024];  tiT [16,18MB);  wT [18,20MB)
// NOTE: reference uses transferi for BOTH projections; transferj unused.
// ---------------------------------------------------------------------------
extern "C" void kernel_launch(void* const* d_in, const int* in_sizes, int n_in,
                              void* d_out, int out_size, void* d_ws, size_t ws_size,
                              hipStream_t stream) {
  const float* x  = (const float*)d_in[0];
  const float* wt = (const float*)d_in[1];
  const float* ti = (const float*)d_in[2];
  float* out = (float*)d_out;

  char* ws = (char*)d_ws;
  const size_t MB = 1024 * 1024;
  const size_t NEED = 152 * MB + NQ * sizeof(float);

  if (ws_size >= NEED) {
    unsigned short* P    = (unsigned short*)ws;
    unsigned char*  xif  = (unsigned char*)(ws + 128 * MB);
    unsigned short* supT = (unsigned short*)(ws + 136 * MB);
    float* lsum          = (float*)(ws + 152 * MB);
    unsigned short* xb   = (unsigned short*)ws;             // transient in P
    unsigned short* tiT  = (unsigned short*)(ws + 16 * MB); // transient in P
    unsigned short* wT   = (unsigned short*)(ws + 18 * MB); // transient in P

    const int n4 = NQ * DD / 4;
    zero_f32<<<NQ / 256, 256, 0, stream>>>(lsum, NQ);
    f32_to_bf16<<<(n4 + 255) / 256, 256, 0, stream>>>(x, xb, n4);
    transpose_cvt<<<dim3(32, 32), 256, 0, stream>>>(ti, tiT, DD, DD);
    transpose_cvt<<<dim3(32, 32), 256, 0, stream>>>(wt, wT, DD, DD);

    // xif[m][n] = e4m3(16 * sum_k xb[m][k]*ti[k][n])
    proj_gemm<DD, true><<<dim3(DD / 128, NQ / 128), 256, 0, stream>>>(xb, tiT, xif);
    // supT[n][m] = bf16(sum_k W[k][n]*x[m][k])
    proj_gemm<NQ, false><<<dim3(NQ / 128, DD / 128), 256, 0, stream>>>(wT, xb, supT);

    qk_fp8<<<dim3(NQ / 128, NQ / 128), 256, 0, stream>>>(xif, P, lsum);
    pv<<<dim3(NQ / 128, DD / 128), 256, 0, stream>>>(P, supT, lsum, out);
  } else {
    float* xi32  = (float*)ws;
    float* sup32 = (float*)(ws + 32 * MB);
    dim3 ggrid(DD / BN, NQ / BM);
    gemm64<<<ggrid, 256, 0, stream>>>(x, ti, xi32, NQ, DD, DD);
    gemm64<<<ggrid, 256, 0, stream>>>(x, wt, sup32, NQ, DD, DD);
    fused_attn<<<NQ / IT, 256, 0, stream>>>(xi32, sup32, out);
  }
}